// Round 1
// baseline (854.591 us; speedup 1.0000x reference)
//
#include <hip/hip_runtime.h>
#include <hip/hip_bf16.h>
#include <type_traits>

typedef __attribute__((ext_vector_type(8))) __bf16 bf16x8;
typedef __attribute__((ext_vector_type(4))) __bf16 bf16x4;
typedef __attribute__((ext_vector_type(4))) float f32x4;
typedef __attribute__((ext_vector_type(4))) unsigned int uintx4;
typedef __attribute__((ext_vector_type(2))) unsigned int uintx2;

__device__ __forceinline__ unsigned short f2bf(float f) {
  __bf16 h = (__bf16)f;
  return __builtin_bit_cast(unsigned short, h);
}
__device__ __forceinline__ float bf2f(unsigned short u) {
  unsigned int x = ((unsigned int)u) << 16;
  return __builtin_bit_cast(float, x);
}
__device__ __forceinline__ bf16x8 ld_frag(const unsigned short* p) {
  return __builtin_bit_cast(bf16x8, *reinterpret_cast<const uintx4*>(p));
}
__device__ __forceinline__ uintx2 cvt4(float4 v) {
  bf16x4 h = { (__bf16)v.x, (__bf16)v.y, (__bf16)v.z, (__bf16)v.w };
  return __builtin_bit_cast(uintx2, h);
}

// ---------------------------------------------------------------------------
// RoPE cos/sin table: [s][i] for s in [0,2048), i in [0,64)
__global__ __launch_bounds__(256)
void rope_table(float2* __restrict__ tab) {
  int gid = blockIdx.x * 256 + threadIdx.x;   // 131072 total
  int i = gid & 63, s = gid >> 6;
  double inv = pow(10000.0, -(double)i / 64.0);
  double ang = (double)s * inv;
  tab[gid] = make_float2((float)cos(ang), (float)sin(ang));
}

// ---------------------------------------------------------------------------
// In-place RoPE on q and k buffers, layout [hb][s][128] bf16, 8 elems/thread
__global__ __launch_bounds__(256)
void rope_kernel(unsigned short* __restrict__ qb, unsigned short* __restrict__ kb,
                 const float2* __restrict__ tab) {
  int gid = blockIdx.x * 256 + threadIdx.x;   // 4,194,304 total
  int g = gid & 15;
  int s = (gid >> 4) & 2047;
  int hb = (gid >> 15) & 63;
  unsigned short* base = (gid >> 21) ? kb : qb;
  size_t off = (((size_t)hb * 2048 + s) * 128) + g * 8;
  union { uintx4 u; unsigned short sh[8]; } v;
  v.u = *reinterpret_cast<const uintx4*>(base + off);
  #pragma unroll
  for (int p = 0; p < 4; ++p) {
    float2 cs = tab[s * 64 + g * 4 + p];
    float x1 = bf2f(v.sh[2 * p]), x2 = bf2f(v.sh[2 * p + 1]);
    float r1 = x1 * cs.x - x2 * cs.y;
    float r2 = x1 * cs.y + x2 * cs.x;
    v.sh[2 * p] = f2bf(r1);
    v.sh[2 * p + 1] = f2bf(r2);
  }
  *reinterpret_cast<uintx4*>(base + off) = v.u;
}

// ---------------------------------------------------------------------------
// V transpose: v[hb][s][d] -> vt[hb][d][s], 64x64 tiles via swizzled LDS
__global__ __launch_bounds__(256)
void transpose_v(const unsigned short* __restrict__ v, unsigned short* __restrict__ vt) {
  __shared__ unsigned short t[64 * 64];
  const int hb = blockIdx.x, s0 = blockIdx.y * 64, d0 = blockIdx.z * 64;
  const int tid = threadIdx.x;
  const size_t vbase = ((size_t)hb * 2048 + s0) * 128 + d0;
  #pragma unroll
  for (int i = 0; i < 2; ++i) {
    int slot = tid + i * 256;             // 512 slots of 8 elems
    int row = slot >> 3, cg = slot & 7;
    uintx4 val = *reinterpret_cast<const uintx4*>(&v[vbase + (size_t)row * 128 + cg * 8]);
    *reinterpret_cast<uintx4*>(&t[row * 64 + ((cg * 8) ^ ((row & 7) << 3))]) = val;
  }
  __syncthreads();
  const size_t obase = ((size_t)hb * 128 + d0) * 2048 + s0;
  #pragma unroll
  for (int i = 0; i < 2; ++i) {
    int slot = tid + i * 256;
    int od = slot >> 3, osg = slot & 7;
    union { uintx4 u; unsigned short sh[8]; } val;
    #pragma unroll
    for (int j = 0; j < 8; ++j) {
      int r = osg * 8 + j;
      val.sh[j] = t[r * 64 + (od ^ ((r & 7) << 3))];
    }
    *reinterpret_cast<uintx4*>(&vt[obase + (size_t)od * 2048 + osg * 8]) = val.u;
  }
}

// ---------------------------------------------------------------------------
// GEMM C[M][N] = A[M][K] @ B[N][K]^T, bf16 MFMA, 128x128 tile, BK=32, 4 waves.
// EPI=0: write fp32 C.  EPI=1: scatter bf16 into q/k/v buffers [h][b][s][d].
template<int EPI, typename TA>
__global__ __launch_bounds__(256)
void gemm_nt(const TA* __restrict__ A, const float* __restrict__ B,
             float* __restrict__ C,
             unsigned short* __restrict__ qb, unsigned short* __restrict__ kb,
             unsigned short* __restrict__ vb, int M, int N, int K) {
  __shared__ unsigned short Alds[128 * 40];   // padded to 40 (80B rows)
  __shared__ unsigned short Blds[128 * 40];
  const int tid = threadIdx.x;
  const int lane = tid & 63;
  const int wid = tid >> 6;
  const int wr = wid >> 1, wc = wid & 1;
  const int l15 = lane & 15, l4 = lane >> 4;
  const int m0 = blockIdx.y * 128, n0 = blockIdx.x * 128;
  const f32x4 z = {0.f, 0.f, 0.f, 0.f};
  f32x4 acc[4][4];
  #pragma unroll
  for (int r = 0; r < 4; ++r)
    #pragma unroll
    for (int c = 0; c < 4; ++c) acc[r][c] = z;

  for (int kt = 0; kt < K; kt += 32) {
    __syncthreads();
    #pragma unroll
    for (int i = 0; i < 4; ++i) {
      const int slot = tid + i * 256;       // 1024 slots: 128 rows x 8 col-groups
      const int row = slot >> 3, cg = slot & 7;
      uintx2 av, bv;
      if constexpr (std::is_same<TA, float>::value) {
        float4 t = *reinterpret_cast<const float4*>(A + (size_t)(m0 + row) * K + kt + cg * 4);
        av = cvt4(t);
      } else {
        av = *reinterpret_cast<const uintx2*>(A + (size_t)(m0 + row) * K + kt + cg * 4);
      }
      float4 t2 = *reinterpret_cast<const float4*>(B + (size_t)(n0 + row) * K + kt + cg * 4);
      bv = cvt4(t2);
      *reinterpret_cast<uintx2*>(&Alds[row * 40 + cg * 4]) = av;
      *reinterpret_cast<uintx2*>(&Blds[row * 40 + cg * 4]) = bv;
    }
    __syncthreads();
    bf16x8 af[4], bfr[4];
    #pragma unroll
    for (int r = 0; r < 4; ++r)
      af[r] = ld_frag(&Alds[(wr * 64 + r * 16 + l15) * 40 + l4 * 8]);
    #pragma unroll
    for (int c = 0; c < 4; ++c)
      bfr[c] = ld_frag(&Blds[(wc * 64 + c * 16 + l15) * 40 + l4 * 8]);
    #pragma unroll
    for (int r = 0; r < 4; ++r)
      #pragma unroll
      for (int c = 0; c < 4; ++c)
        acc[r][c] = __builtin_amdgcn_mfma_f32_16x16x32_bf16(af[r], bfr[c], acc[r][c], 0, 0, 0);
  }

  if constexpr (EPI == 0) {
    #pragma unroll
    for (int r = 0; r < 4; ++r)
      #pragma unroll
      for (int c = 0; c < 4; ++c) {
        const int col = n0 + wc * 64 + c * 16 + l15;
        #pragma unroll
        for (int j = 0; j < 4; ++j) {
          const int row = m0 + wr * 64 + r * 16 + l4 * 4 + j;
          C[(size_t)row * N + col] = acc[r][c][j];
        }
      }
  } else {
    #pragma unroll
    for (int c = 0; c < 4; ++c) {
      const int col = n0 + wc * 64 + c * 16 + l15;
      const int t = col >> 11, h = (col >> 7) & 15, d = col & 127;
      unsigned short* base = (t == 0) ? qb : ((t == 1) ? kb : vb);
      #pragma unroll
      for (int r = 0; r < 4; ++r)
        #pragma unroll
        for (int j = 0; j < 4; ++j) {
          const int row = m0 + wr * 64 + r * 16 + l4 * 4 + j;
          const int b = row >> 11, s = row & 2047;
          base[(((size_t)(h * 4 + b)) * 2048 + s) * 128 + d] = f2bf(acc[r][c][j]);
        }
    }
  }
}

// ---------------------------------------------------------------------------
// Causal flash attention. q,k: [hb][s][128] bf16 (roped); vt: [hb][d][s] bf16.
// Output a: [b*2048+s][h*128+d] bf16. QBLK=64 (16 rows/wave), KBLK=64.
__global__ __launch_bounds__(256)
void attn_kernel(const unsigned short* __restrict__ q,
                 const unsigned short* __restrict__ k,
                 const unsigned short* __restrict__ vt,
                 unsigned short* __restrict__ a) {
  const int hb = blockIdx.x;            // h*4 + b
  const int h = hb >> 2, b = hb & 3;
  const int qb = 31 - blockIdx.y;       // heavy blocks first
  const int q0 = qb * 64;
  const int tid = threadIdx.x, w = tid >> 6, lane = tid & 63;
  const int l15 = lane & 15, l4 = lane >> 4;

  __shared__ unsigned short Klds[64 * 128];   // XOR-swizzled rows
  __shared__ unsigned short Vlds[128 * 64];   // vt tile, XOR-swizzled rows
  __shared__ unsigned short Plds[4][16 * 64]; // per-wave P, swizzled

  const size_t qkbase = (size_t)hb * 2048 * 128;
  const size_t vtbase = (size_t)hb * 128 * 2048;
  const int qw_min = q0 + w * 16;
  const int qrow_l = qw_min + l15;
  const float scale = 0.08838834764831845f;   // 1/sqrt(128)

  bf16x8 qf[4];
  #pragma unroll
  for (int ks = 0; ks < 4; ++ks)
    qf[ks] = ld_frag(&q[qkbase + (size_t)qrow_l * 128 + ks * 32 + l4 * 8]);

  float m[4], lsum[4];
  f32x4 acco[8];
  const f32x4 z = {0.f, 0.f, 0.f, 0.f};
  #pragma unroll
  for (int j = 0; j < 4; ++j) { m[j] = -1e30f; lsum[j] = 0.f; }
  #pragma unroll
  for (int d2 = 0; d2 < 8; ++d2) acco[d2] = z;

  for (int kt = 0; kt <= q0; kt += 64) {
    __syncthreads();
    // stage K tile (64 rows x 128 cols)
    #pragma unroll
    for (int i = 0; i < 4; ++i) {
      int slot = tid + i * 256;
      int row = slot >> 4, cg = slot & 15;
      uintx4 val = *reinterpret_cast<const uintx4*>(&k[qkbase + (size_t)(kt + row) * 128 + cg * 8]);
      *reinterpret_cast<uintx4*>(&Klds[row * 128 + ((cg * 8) ^ ((row & 7) << 3))]) = val;
    }
    // stage Vt tile (128 rows x 64 cols)
    #pragma unroll
    for (int i = 0; i < 4; ++i) {
      int slot = tid + i * 256;
      int row = slot >> 3, cg = slot & 7;
      uintx4 val = *reinterpret_cast<const uintx4*>(&vt[vtbase + (size_t)row * 2048 + kt + cg * 8]);
      *reinterpret_cast<uintx4*>(&Vlds[row * 64 + ((cg * 8) ^ ((row & 7) << 3))]) = val;
    }
    __syncthreads();

    // S = Q @ K^T  (per wave: 16q x 64kv)
    f32x4 sc[4];
    #pragma unroll
    for (int c = 0; c < 4; ++c) sc[c] = z;
    #pragma unroll
    for (int c = 0; c < 4; ++c) {
      const int kr = c * 16 + l15;
      #pragma unroll
      for (int ks = 0; ks < 4; ++ks) {
        bf16x8 kf = ld_frag(&Klds[kr * 128 + ((l4 * 8 + ks * 32) ^ ((kr & 7) << 3))]);
        sc[c] = __builtin_amdgcn_mfma_f32_16x16x32_bf16(qf[ks], kf, sc[c], 0, 0, 0);
      }
    }
    // scale + causal mask
    #pragma unroll
    for (int c = 0; c < 4; ++c) {
      const int kvg = kt + c * 16 + l15;
      #pragma unroll
      for (int j = 0; j < 4; ++j) {
        const int qg = qw_min + l4 * 4 + j;
        float s = sc[c][j] * scale;
        sc[c][j] = (kvg > qg) ? -1e30f : s;
      }
    }
    // online softmax
    float mx[4];
    #pragma unroll
    for (int j = 0; j < 4; ++j)
      mx[j] = fmaxf(fmaxf(sc[0][j], sc[1][j]), fmaxf(sc[2][j], sc[3][j]));
    #pragma unroll
    for (int off = 1; off < 16; off <<= 1)
      #pragma unroll
      for (int j = 0; j < 4; ++j) mx[j] = fmaxf(mx[j], __shfl_xor(mx[j], off));
    float alpha[4];
    #pragma unroll
    for (int j = 0; j < 4; ++j) {
      float nm = fmaxf(m[j], mx[j]);
      alpha[j] = __expf(m[j] - nm);
      m[j] = nm;
    }
    float rs[4] = {0.f, 0.f, 0.f, 0.f};
    #pragma unroll
    for (int c = 0; c < 4; ++c)
      #pragma unroll
      for (int j = 0; j < 4; ++j) {
        float p = __expf(sc[c][j] - m[j]);
        sc[c][j] = p;
        rs[j] += p;
      }
    #pragma unroll
    for (int off = 1; off < 16; off <<= 1)
      #pragma unroll
      for (int j = 0; j < 4; ++j) rs[j] += __shfl_xor(rs[j], off);
    #pragma unroll
    for (int j = 0; j < 4; ++j) lsum[j] = lsum[j] * alpha[j] + rs[j];
    #pragma unroll
    for (int d2 = 0; d2 < 8; ++d2)
      #pragma unroll
      for (int j = 0; j < 4; ++j) acco[d2][j] *= alpha[j];
    // P -> LDS (bf16, swizzled)
    #pragma unroll
    for (int c = 0; c < 4; ++c)
      #pragma unroll
      for (int j = 0; j < 4; ++j) {
        const int qr = l4 * 4 + j;
        const int kv = c * 16 + l15;
        Plds[w][qr * 64 + (kv ^ ((qr & 7) << 3))] = f2bf(sc[c][j]);
      }
    // O += P @ V
    #pragma unroll
    for (int g = 0; g < 2; ++g) {
      bf16x8 pf = ld_frag(&Plds[w][l15 * 64 + ((g * 32 + l4 * 8) ^ ((l15 & 7) << 3))]);
      #pragma unroll
      for (int d2 = 0; d2 < 8; ++d2) {
        const int dr = d2 * 16 + l15;
        bf16x8 vf = ld_frag(&Vlds[dr * 64 + ((g * 32 + l4 * 8) ^ ((dr & 7) << 3))]);
        acco[d2] = __builtin_amdgcn_mfma_f32_16x16x32_bf16(pf, vf, acco[d2], 0, 0, 0);
      }
    }
  }

  // normalize + write a[b*2048+s][h*128+d] bf16
  #pragma unroll
  for (int j = 0; j < 4; ++j) {
    const float inv = 1.0f / lsum[j];
    const int sr = qw_min + l4 * 4 + j;
    const size_t abase = ((size_t)(b * 2048 + sr)) * 2048 + h * 128;
    #pragma unroll
    for (int d2 = 0; d2 < 8; ++d2)
      a[abase + d2 * 16 + l15] = f2bf(acco[d2][j] * inv);
  }
}

// ---------------------------------------------------------------------------
extern "C" void kernel_launch(void* const* d_in, const int* in_sizes, int n_in,
                              void* d_out, int out_size, void* d_ws, size_t ws_size,
                              hipStream_t stream) {
  const float* x = (const float*)d_in[0];
  const float* wqkv = (const float*)d_in[1];
  const float* wout = (const float*)d_in[2];
  float* out = (float*)d_out;
  char* ws = (char*)d_ws;

  unsigned short* qbuf = (unsigned short*)(ws + 0);           // 33,554,432 B
  unsigned short* kbuf = (unsigned short*)(ws + 33554432);    // 33,554,432 B
  unsigned short* vtb  = (unsigned short*)(ws + 67108864);    // 33,554,432 B
  unsigned short* abuf = (unsigned short*)(ws + 100663296);   // 33,554,432 B (also v_temp)
  float2* tab = (float2*)(ws + 134217728);                    // 1,048,576 B

  hipLaunchKernelGGL(rope_table, dim3(512), dim3(256), 0, stream, tab);
  // QKV projection; v goes to abuf (v_temp, dead before attention writes a)
  hipLaunchKernelGGL((gemm_nt<1, float>), dim3(48, 64), dim3(256), 0, stream,
                     x, wqkv, out, qbuf, kbuf, abuf, 8192, 6144, 2048);
  hipLaunchKernelGGL(rope_kernel, dim3(16384), dim3(256), 0, stream,
                     qbuf, kbuf, (const float2*)tab);
  hipLaunchKernelGGL(transpose_v, dim3(64, 32, 2), dim3(256), 0, stream, abuf, vtb);
  hipLaunchKernelGGL(attn_kernel, dim3(64, 32), dim3(256), 0, stream,
                     qbuf, kbuf, vtb, abuf);
  hipLaunchKernelGGL((gemm_nt<0, unsigned short>), dim3(16, 64), dim3(256), 0, stream,
                     abuf, wout, out, nullptr, nullptr, nullptr, 8192, 2048, 2048);
}

// Round 2
// 669.605 us; speedup vs baseline: 1.2763x; 1.2763x over previous
//
#include <hip/hip_runtime.h>
#include <hip/hip_bf16.h>

typedef __attribute__((ext_vector_type(8))) __bf16 bf16x8;
typedef __attribute__((ext_vector_type(4))) __bf16 bf16x4;
typedef __attribute__((ext_vector_type(4))) float f32x4;
typedef __attribute__((ext_vector_type(4))) unsigned int uintx4;
typedef __attribute__((ext_vector_type(2))) unsigned int uintx2;

__device__ __forceinline__ unsigned short f2bf(float f) {
  __bf16 h = (__bf16)f;
  return __builtin_bit_cast(unsigned short, h);
}
__device__ __forceinline__ float bf2f(unsigned short u) {
  unsigned int x = ((unsigned int)u) << 16;
  return __builtin_bit_cast(float, x);
}
__device__ __forceinline__ bf16x8 ld_frag(const unsigned short* p) {
  return __builtin_bit_cast(bf16x8, *reinterpret_cast<const uintx4*>(p));
}
__device__ __forceinline__ uintx2 cvt4(float4 v) {
  bf16x4 h = { (__bf16)v.x, (__bf16)v.y, (__bf16)v.z, (__bf16)v.w };
  return __builtin_bit_cast(uintx2, h);
}
// async global->LDS, 16B per lane; lds dest must be wave-uniform base
__device__ __forceinline__ void gload16(const unsigned short* g, unsigned short* l) {
  __builtin_amdgcn_global_load_lds(
      (const __attribute__((address_space(1))) void*)g,
      (__attribute__((address_space(3))) void*)l, 16, 0, 0);
}

// ---------------------------------------------------------------------------
// fp32 -> bf16 bulk convert, 8 elems/thread (n must be multiple of 2048)
__global__ __launch_bounds__(256)
void cvt_bf16(const float* __restrict__ in, unsigned short* __restrict__ out, int n8) {
  int gid = blockIdx.x * 256 + threadIdx.x;
  if (gid >= n8) return;
  const float4* p = reinterpret_cast<const float4*>(in) + (size_t)gid * 2;
  float4 a = p[0], b = p[1];
  uintx2 lo = cvt4(a), hi = cvt4(b);
  uintx4 o = { lo[0], lo[1], hi[0], hi[1] };
  *(reinterpret_cast<uintx4*>(out) + gid) = o;
}

// ---------------------------------------------------------------------------
// RoPE cos/sin table: [s][i] for s in [0,2048), i in [0,64)
__global__ __launch_bounds__(256)
void rope_table(float2* __restrict__ tab) {
  int gid = blockIdx.x * 256 + threadIdx.x;   // 131072 total
  int i = gid & 63, s = gid >> 6;
  double inv = pow(10000.0, -(double)i / 64.0);
  double ang = (double)s * inv;
  tab[gid] = make_float2((float)cos(ang), (float)sin(ang));
}

// ---------------------------------------------------------------------------
// In-place RoPE on q and k buffers, layout [hb][s][128] bf16, 8 elems/thread
__global__ __launch_bounds__(256)
void rope_kernel(unsigned short* __restrict__ qb, unsigned short* __restrict__ kb,
                 const float2* __restrict__ tab) {
  int gid = blockIdx.x * 256 + threadIdx.x;   // 4,194,304 total
  int g = gid & 15;
  int s = (gid >> 4) & 2047;
  int hb = (gid >> 15) & 63;
  unsigned short* base = (gid >> 21) ? kb : qb;
  size_t off = (((size_t)hb * 2048 + s) * 128) + g * 8;
  union { uintx4 u; unsigned short sh[8]; } v;
  v.u = *reinterpret_cast<const uintx4*>(base + off);
  #pragma unroll
  for (int p = 0; p < 4; ++p) {
    float2 cs = tab[s * 64 + g * 4 + p];
    float x1 = bf2f(v.sh[2 * p]), x2 = bf2f(v.sh[2 * p + 1]);
    float r1 = x1 * cs.x - x2 * cs.y;
    float r2 = x1 * cs.y + x2 * cs.x;
    v.sh[2 * p] = f2bf(r1);
    v.sh[2 * p + 1] = f2bf(r2);
  }
  *reinterpret_cast<uintx4*>(base + off) = v.u;
}

// ---------------------------------------------------------------------------
// GEMM C[M][N] = A[M][K] @ B[N][K]^T, bf16 in, m97 structure:
// 128x128 tile, BK=64, global_load_lds w16 (linear dest, pre-swizzled src),
// XOR-swizzled ds_read_b128, bijective XCD swizzle (nwg % 8 == 0).
// EPI=0: fp32 C.  EPI=1: scatter bf16 q/k [hb][s][128] + V transposed [hb][d][s].
template<int EPI>
__global__ __launch_bounds__(256)
void gemm_bf16(const unsigned short* __restrict__ A, const unsigned short* __restrict__ B,
               float* __restrict__ C,
               unsigned short* __restrict__ qb, unsigned short* __restrict__ kb,
               unsigned short* __restrict__ vtb, int M, int N, int K, int nbx) {
  __shared__ unsigned short Alds[128 * 64];
  __shared__ unsigned short Blds[128 * 64];
  const int nwg = gridDim.x;
  const int bid = blockIdx.x;
  const int swz = (bid & 7) * (nwg >> 3) + (bid >> 3);
  const int n0 = (swz % nbx) * 128, m0 = (swz / nbx) * 128;
  const int tid = threadIdx.x, lane = tid & 63, w = tid >> 6;
  const int wr = w >> 1, wc = w & 1, l15 = lane & 15, l4 = lane >> 4;
  const int srow = lane >> 3;           // 0..7: row within 8-row stage group
  const int scol = (lane & 7) * 8;      // shorts: 16B col group

  const f32x4 z = {0.f, 0.f, 0.f, 0.f};
  f32x4 acc[4][4];
  #pragma unroll
  for (int r = 0; r < 4; ++r)
    #pragma unroll
    for (int c = 0; c < 4; ++c) acc[r][c] = z;

  for (int kt = 0; kt < K; kt += 64) {
    __syncthreads();
    #pragma unroll
    for (int i = 0; i < 4; ++i) {
      const int rb = (i * 4 + w) * 8;       // wave-uniform row base
      const int R = rb + srow;
      const int cs = scol ^ ((R & 7) << 3); // pre-swizzled source col (shorts)
      gload16(&A[(size_t)(m0 + R) * K + kt + cs], &Alds[rb * 64]);
      gload16(&B[(size_t)(n0 + R) * K + kt + cs], &Blds[rb * 64]);
    }
    __syncthreads();
    bf16x8 af[2][4], bfr[2][4];
    #pragma unroll
    for (int kk = 0; kk < 2; ++kk)
      #pragma unroll
      for (int r = 0; r < 4; ++r) {
        const int Ra = wr * 64 + r * 16 + l15;
        af[kk][r] = ld_frag(&Alds[Ra * 64 + ((kk * 32 + l4 * 8) ^ ((Ra & 7) << 3))]);
        const int Rb = wc * 64 + r * 16 + l15;
        bfr[kk][r] = ld_frag(&Blds[Rb * 64 + ((kk * 32 + l4 * 8) ^ ((Rb & 7) << 3))]);
      }
    #pragma unroll
    for (int r = 0; r < 4; ++r)
      #pragma unroll
      for (int c = 0; c < 4; ++c)
        #pragma unroll
        for (int kk = 0; kk < 2; ++kk)
          acc[r][c] = __builtin_amdgcn_mfma_f32_16x16x32_bf16(af[kk][r], bfr[kk][c], acc[r][c], 0, 0, 0);
  }

  if constexpr (EPI == 0) {
    #pragma unroll
    for (int r = 0; r < 4; ++r)
      #pragma unroll
      for (int c = 0; c < 4; ++c) {
        const int col = n0 + wc * 64 + c * 16 + l15;
        #pragma unroll
        for (int j = 0; j < 4; ++j) {
          const int row = m0 + wr * 64 + r * 16 + l4 * 4 + j;
          C[(size_t)row * N + col] = acc[r][c][j];
        }
      }
  } else {
    #pragma unroll
    for (int c = 0; c < 4; ++c) {
      const int col = n0 + wc * 64 + c * 16 + l15;
      const int t = col >> 11, h = (col >> 7) & 15, d = col & 127;
      #pragma unroll
      for (int r = 0; r < 4; ++r) {
        const int row0 = m0 + wr * 64 + r * 16 + l4 * 4;
        const int b = row0 >> 11, s0 = row0 & 2047;
        if (t == 2) {
          bf16x4 v4 = { (__bf16)acc[r][c][0], (__bf16)acc[r][c][1],
                        (__bf16)acc[r][c][2], (__bf16)acc[r][c][3] };
          *reinterpret_cast<uintx2*>(&vtb[(((size_t)(h * 4 + b)) * 128 + d) * 2048 + s0]) =
              __builtin_bit_cast(uintx2, v4);
        } else {
          unsigned short* base = t ? kb : qb;
          #pragma unroll
          for (int j = 0; j < 4; ++j)
            base[(((size_t)(h * 4 + b)) * 2048 + s0 + j) * 128 + d] = f2bf(acc[r][c][j]);
        }
      }
    }
  }
}

// ---------------------------------------------------------------------------
// Causal flash attention. q,k: [hb][s][128] bf16 (roped); vt: [hb][d][s] bf16.
// Output a: [b*2048+s][h*128+d] bf16. QBLK=64 (16 rows/wave), KBLK=64.
__global__ __launch_bounds__(256)
void attn_kernel(const unsigned short* __restrict__ q,
                 const unsigned short* __restrict__ k,
                 const unsigned short* __restrict__ vt,
                 unsigned short* __restrict__ a) {
  const int hb = blockIdx.x;            // h*4 + b
  const int h = hb >> 2, b = hb & 3;
  const int qb = 31 - blockIdx.y;       // heavy blocks first
  const int q0 = qb * 64;
  const int tid = threadIdx.x, w = tid >> 6, lane = tid & 63;
  const int l15 = lane & 15, l4 = lane >> 4;

  __shared__ unsigned short Klds[64 * 128];   // XOR-swizzled rows
  __shared__ unsigned short Vlds[128 * 64];   // vt tile, XOR-swizzled rows
  __shared__ unsigned short Plds[4][16 * 64]; // per-wave P, swizzled

  const size_t qkbase = (size_t)hb * 2048 * 128;
  const size_t vtbase = (size_t)hb * 128 * 2048;
  const int qw_min = q0 + w * 16;
  const int qrow_l = qw_min + l15;
  const float scale = 0.08838834764831845f;   // 1/sqrt(128)

  bf16x8 qf[4];
  #pragma unroll
  for (int ks = 0; ks < 4; ++ks)
    qf[ks] = ld_frag(&q[qkbase + (size_t)qrow_l * 128 + ks * 32 + l4 * 8]);

  float m[4], lsum[4];
  f32x4 acco[8];
  const f32x4 z = {0.f, 0.f, 0.f, 0.f};
  #pragma unroll
  for (int j = 0; j < 4; ++j) { m[j] = -1e30f; lsum[j] = 0.f; }
  #pragma unroll
  for (int d2 = 0; d2 < 8; ++d2) acco[d2] = z;

  for (int kt = 0; kt <= q0; kt += 64) {
    __syncthreads();
    // stage K tile (64 rows x 128 cols)
    #pragma unroll
    for (int i = 0; i < 4; ++i) {
      int slot = tid + i * 256;
      int row = slot >> 4, cg = slot & 15;
      uintx4 val = *reinterpret_cast<const uintx4*>(&k[qkbase + (size_t)(kt + row) * 128 + cg * 8]);
      *reinterpret_cast<uintx4*>(&Klds[row * 128 + ((cg * 8) ^ ((row & 7) << 3))]) = val;
    }
    // stage Vt tile (128 rows x 64 cols)
    #pragma unroll
    for (int i = 0; i < 4; ++i) {
      int slot = tid + i * 256;
      int row = slot >> 3, cg = slot & 7;
      uintx4 val = *reinterpret_cast<const uintx4*>(&vt[vtbase + (size_t)row * 2048 + kt + cg * 8]);
      *reinterpret_cast<uintx4*>(&Vlds[row * 64 + ((cg * 8) ^ ((row & 7) << 3))]) = val;
    }
    __syncthreads();

    // S = Q @ K^T  (per wave: 16q x 64kv)
    f32x4 sc[4];
    #pragma unroll
    for (int c = 0; c < 4; ++c) sc[c] = z;
    #pragma unroll
    for (int c = 0; c < 4; ++c) {
      const int kr = c * 16 + l15;
      #pragma unroll
      for (int ks = 0; ks < 4; ++ks) {
        bf16x8 kf = ld_frag(&Klds[kr * 128 + ((l4 * 8 + ks * 32) ^ ((kr & 7) << 3))]);
        sc[c] = __builtin_amdgcn_mfma_f32_16x16x32_bf16(qf[ks], kf, sc[c], 0, 0, 0);
      }
    }
    // scale + causal mask
    #pragma unroll
    for (int c = 0; c < 4; ++c) {
      const int kvg = kt + c * 16 + l15;
      #pragma unroll
      for (int j = 0; j < 4; ++j) {
        const int qg = qw_min + l4 * 4 + j;
        float s = sc[c][j] * scale;
        sc[c][j] = (kvg > qg) ? -1e30f : s;
      }
    }
    // online softmax
    float mx[4];
    #pragma unroll
    for (int j = 0; j < 4; ++j)
      mx[j] = fmaxf(fmaxf(sc[0][j], sc[1][j]), fmaxf(sc[2][j], sc[3][j]));
    #pragma unroll
    for (int off = 1; off < 16; off <<= 1)
      #pragma unroll
      for (int j = 0; j < 4; ++j) mx[j] = fmaxf(mx[j], __shfl_xor(mx[j], off));
    float alpha[4];
    #pragma unroll
    for (int j = 0; j < 4; ++j) {
      float nm = fmaxf(m[j], mx[j]);
      alpha[j] = __expf(m[j] - nm);
      m[j] = nm;
    }
    float rs[4] = {0.f, 0.f, 0.f, 0.f};
    #pragma unroll
    for (int c = 0; c < 4; ++c)
      #pragma unroll
      for (int j = 0; j < 4; ++j) {
        float p = __expf(sc[c][j] - m[j]);
        sc[c][j] = p;
        rs[j] += p;
      }
    #pragma unroll
    for (int off = 1; off < 16; off <<= 1)
      #pragma unroll
      for (int j = 0; j < 4; ++j) rs[j] += __shfl_xor(rs[j], off);
    #pragma unroll
    for (int j = 0; j < 4; ++j) lsum[j] = lsum[j] * alpha[j] + rs[j];
    #pragma unroll
    for (int d2 = 0; d2 < 8; ++d2)
      #pragma unroll
      for (int j = 0; j < 4; ++j) acco[d2][j] *= alpha[j];
    // P -> LDS (bf16, swizzled)
    #pragma unroll
    for (int c = 0; c < 4; ++c)
      #pragma unroll
      for (int j = 0; j < 4; ++j) {
        const int qr = l4 * 4 + j;
        const int kv = c * 16 + l15;
        Plds[w][qr * 64 + (kv ^ ((qr & 7) << 3))] = f2bf(sc[c][j]);
      }
    // O += P @ V
    #pragma unroll
    for (int g = 0; g < 2; ++g) {
      bf16x8 pf = ld_frag(&Plds[w][l15 * 64 + ((g * 32 + l4 * 8) ^ ((l15 & 7) << 3))]);
      #pragma unroll
      for (int d2 = 0; d2 < 8; ++d2) {
        const int dr = d2 * 16 + l15;
        bf16x8 vf = ld_frag(&Vlds[dr * 64 + ((g * 32 + l4 * 8) ^ ((dr & 7) << 3))]);
        acco[d2] = __builtin_amdgcn_mfma_f32_16x16x32_bf16(pf, vf, acco[d2], 0, 0, 0);
      }
    }
  }

  // normalize + write a[b*2048+s][h*128+d] bf16
  #pragma unroll
  for (int j = 0; j < 4; ++j) {
    const float inv = 1.0f / lsum[j];
    const int sr = qw_min + l4 * 4 + j;
    const size_t abase = ((size_t)(b * 2048 + sr)) * 2048 + h * 128;
    #pragma unroll
    for (int d2 = 0; d2 < 8; ++d2)
      a[abase + d2 * 16 + l15] = f2bf(acco[d2][j] * inv);
  }
}

// ---------------------------------------------------------------------------
extern "C" void kernel_launch(void* const* d_in, const int* in_sizes, int n_in,
                              void* d_out, int out_size, void* d_ws, size_t ws_size,
                              hipStream_t stream) {
  const float* x = (const float*)d_in[0];
  const float* wqkv = (const float*)d_in[1];
  const float* wout = (const float*)d_in[2];
  float* out = (float*)d_out;
  char* ws = (char*)d_ws;
  char* ob = (char*)d_out;

  // ws (128 MiB): q, k, vt, a  (w_out bf16 reuses dead q region at the end)
  unsigned short* qbuf = (unsigned short*)(ws + 0);
  unsigned short* kbuf = (unsigned short*)(ws + 33554432);
  unsigned short* vtb  = (unsigned short*)(ws + 67108864);
  unsigned short* abuf = (unsigned short*)(ws + 100663296);
  unsigned short* woutb = qbuf;  // converted AFTER attn (q dead by then)
  // d_out (64 MB) as scratch until the final GEMM overwrites it:
  unsigned short* xb    = (unsigned short*)(ob + 0);          // 33.5 MB
  unsigned short* wqkvb = (unsigned short*)(ob + 33554432);   // 25.2 MB
  float2*         tab   = (float2*)(ob + 58720256);           // 1 MB

  hipLaunchKernelGGL(cvt_bf16, dim3(8192), dim3(256), 0, stream, x, xb, 2097152);
  hipLaunchKernelGGL(cvt_bf16, dim3(6144), dim3(256), 0, stream, wqkv, wqkvb, 1572864);
  hipLaunchKernelGGL(rope_table, dim3(512), dim3(256), 0, stream, tab);
  // QKV projection: q,k -> [hb][s][d]; V scattered transposed -> vt [hb][d][s]
  hipLaunchKernelGGL((gemm_bf16<1>), dim3(3072), dim3(256), 0, stream,
                     xb, wqkvb, nullptr, qbuf, kbuf, vtb, 8192, 6144, 2048, 48);
  hipLaunchKernelGGL(rope_kernel, dim3(16384), dim3(256), 0, stream,
                     qbuf, kbuf, (const float2*)tab);
  hipLaunchKernelGGL(attn_kernel, dim3(64, 32), dim3(256), 0, stream,
                     qbuf, kbuf, vtb, abuf);
  hipLaunchKernelGGL(cvt_bf16, dim3(2048), dim3(256), 0, stream, wout, woutb, 524288);
  hipLaunchKernelGGL((gemm_bf16<0>), dim3(1024), dim3(256), 0, stream,
                     abuf, woutb, out, nullptr, nullptr, nullptr, 8192, 2048, 2048, 16);
}

// Round 3
// 580.852 us; speedup vs baseline: 1.4713x; 1.1528x over previous
//
#include <hip/hip_runtime.h>
#include <hip/hip_bf16.h>

typedef __attribute__((ext_vector_type(8))) __bf16 bf16x8;
typedef __attribute__((ext_vector_type(4))) __bf16 bf16x4;
typedef __attribute__((ext_vector_type(4))) float f32x4;
typedef __attribute__((ext_vector_type(4))) unsigned int uintx4;
typedef __attribute__((ext_vector_type(2))) unsigned int uintx2;

__device__ __forceinline__ unsigned short f2bf(float f) {
  __bf16 h = (__bf16)f;
  return __builtin_bit_cast(unsigned short, h);
}
__device__ __forceinline__ float bf2f(unsigned short u) {
  unsigned int x = ((unsigned int)u) << 16;
  return __builtin_bit_cast(float, x);
}
__device__ __forceinline__ bf16x8 ld_frag(const unsigned short* p) {
  return __builtin_bit_cast(bf16x8, *reinterpret_cast<const uintx4*>(p));
}
__device__ __forceinline__ uintx2 cvt4(float4 v) {
  bf16x4 h = { (__bf16)v.x, (__bf16)v.y, (__bf16)v.z, (__bf16)v.w };
  return __builtin_bit_cast(uintx2, h);
}
// async global->LDS, 16B per lane; lds dest must be wave-uniform base
__device__ __forceinline__ void gload16(const unsigned short* g, unsigned short* l) {
  __builtin_amdgcn_global_load_lds(
      (const __attribute__((address_space(1))) void*)g,
      (__attribute__((address_space(3))) void*)l, 16, 0, 0);
}

// ---------------------------------------------------------------------------
// fp32 -> bf16 bulk convert, 8 elems/thread
__global__ __launch_bounds__(256)
void cvt_bf16(const float* __restrict__ in, unsigned short* __restrict__ out, int n8) {
  int gid = blockIdx.x * 256 + threadIdx.x;
  if (gid >= n8) return;
  const float4* p = reinterpret_cast<const float4*>(in) + (size_t)gid * 2;
  float4 a = p[0], b = p[1];
  uintx2 lo = cvt4(a), hi = cvt4(b);
  uintx4 o = { lo[0], lo[1], hi[0], hi[1] };
  *(reinterpret_cast<uintx4*>(out) + gid) = o;
}

// ---------------------------------------------------------------------------
// RoPE cos/sin table: [s][i] for s in [0,2048), i in [0,64)
__global__ __launch_bounds__(256)
void rope_table(float2* __restrict__ tab) {
  int gid = blockIdx.x * 256 + threadIdx.x;   // 131072 total
  int i = gid & 63, s = gid >> 6;
  double inv = pow(10000.0, -(double)i / 64.0);
  double ang = (double)s * inv;
  tab[gid] = make_float2((float)cos(ang), (float)sin(ang));
}

// ---------------------------------------------------------------------------
// In-place RoPE on q and k buffers, layout [hb][s][128] bf16, 8 elems/thread
__global__ __launch_bounds__(256)
void rope_kernel(unsigned short* __restrict__ qb, unsigned short* __restrict__ kb,
                 const float2* __restrict__ tab) {
  int gid = blockIdx.x * 256 + threadIdx.x;   // 4,194,304 total
  int g = gid & 15;
  int s = (gid >> 4) & 2047;
  int hb = (gid >> 15) & 63;
  unsigned short* base = (gid >> 21) ? kb : qb;
  size_t off = (((size_t)hb * 2048 + s) * 128) + g * 8;
  union { uintx4 u; unsigned short sh[8]; } v;
  v.u = *reinterpret_cast<const uintx4*>(base + off);
  #pragma unroll
  for (int p = 0; p < 4; ++p) {
    float2 cs = tab[s * 64 + g * 4 + p];
    float x1 = bf2f(v.sh[2 * p]), x2 = bf2f(v.sh[2 * p + 1]);
    float r1 = x1 * cs.x - x2 * cs.y;
    float r2 = x1 * cs.y + x2 * cs.x;
    v.sh[2 * p] = f2bf(r1);
    v.sh[2 * p + 1] = f2bf(r2);
  }
  *reinterpret_cast<uintx4*>(base + off) = v.u;
}

// ---------------------------------------------------------------------------
// GEMM C[M][N] = A[M][K] @ B[N][K]^T, bf16 in, m97 structure:
// 128x128 tile, BK=64, global_load_lds w16 (linear dest, pre-swizzled src),
// XOR-swizzled ds_read_b128, bijective XCD swizzle (nwg % 8 == 0).
// EPI=0: fp32 C.  EPI=1: scatter bf16 q/k [hb][s][128] + V transposed [hb][d][s].
template<int EPI>
__global__ __launch_bounds__(256)
void gemm_bf16(const unsigned short* __restrict__ A, const unsigned short* __restrict__ B,
               float* __restrict__ C,
               unsigned short* __restrict__ qb, unsigned short* __restrict__ kb,
               unsigned short* __restrict__ vtb, int M, int N, int K, int nbx) {
  __shared__ unsigned short Alds[128 * 64];
  __shared__ unsigned short Blds[128 * 64];
  const int nwg = gridDim.x;
  const int bid = blockIdx.x;
  const int swz = (bid & 7) * (nwg >> 3) + (bid >> 3);
  const int n0 = (swz % nbx) * 128, m0 = (swz / nbx) * 128;
  const int tid = threadIdx.x, lane = tid & 63, w = tid >> 6;
  const int wr = w >> 1, wc = w & 1, l15 = lane & 15, l4 = lane >> 4;
  const int srow = lane >> 3;           // 0..7: row within 8-row stage group
  const int scol = (lane & 7) * 8;      // shorts: 16B col group

  const f32x4 z = {0.f, 0.f, 0.f, 0.f};
  f32x4 acc[4][4];
  #pragma unroll
  for (int r = 0; r < 4; ++r)
    #pragma unroll
    for (int c = 0; c < 4; ++c) acc[r][c] = z;

  for (int kt = 0; kt < K; kt += 64) {
    __syncthreads();
    #pragma unroll
    for (int i = 0; i < 4; ++i) {
      const int rb = (i * 4 + w) * 8;       // wave-uniform row base
      const int R = rb + srow;
      const int cs = scol ^ ((R & 7) << 3); // pre-swizzled source col (shorts)
      gload16(&A[(size_t)(m0 + R) * K + kt + cs], &Alds[rb * 64]);
      gload16(&B[(size_t)(n0 + R) * K + kt + cs], &Blds[rb * 64]);
    }
    __syncthreads();
    bf16x8 af[2][4], bfr[2][4];
    #pragma unroll
    for (int kk = 0; kk < 2; ++kk)
      #pragma unroll
      for (int r = 0; r < 4; ++r) {
        const int Ra = wr * 64 + r * 16 + l15;
        af[kk][r] = ld_frag(&Alds[Ra * 64 + ((kk * 32 + l4 * 8) ^ ((Ra & 7) << 3))]);
        const int Rb = wc * 64 + r * 16 + l15;
        bfr[kk][r] = ld_frag(&Blds[Rb * 64 + ((kk * 32 + l4 * 8) ^ ((Rb & 7) << 3))]);
      }
    #pragma unroll
    for (int r = 0; r < 4; ++r)
      #pragma unroll
      for (int c = 0; c < 4; ++c)
        #pragma unroll
        for (int kk = 0; kk < 2; ++kk)
          acc[r][c] = __builtin_amdgcn_mfma_f32_16x16x32_bf16(af[kk][r], bfr[kk][c], acc[r][c], 0, 0, 0);
  }

  if constexpr (EPI == 0) {
    #pragma unroll
    for (int r = 0; r < 4; ++r)
      #pragma unroll
      for (int c = 0; c < 4; ++c) {
        const int col = n0 + wc * 64 + c * 16 + l15;
        #pragma unroll
        for (int j = 0; j < 4; ++j) {
          const int row = m0 + wr * 64 + r * 16 + l4 * 4 + j;
          C[(size_t)row * N + col] = acc[r][c][j];
        }
      }
  } else {
    #pragma unroll
    for (int c = 0; c < 4; ++c) {
      const int col = n0 + wc * 64 + c * 16 + l15;
      const int t = col >> 11, h = (col >> 7) & 15, d = col & 127;
      #pragma unroll
      for (int r = 0; r < 4; ++r) {
        const int row0 = m0 + wr * 64 + r * 16 + l4 * 4;
        const int b = row0 >> 11, s0 = row0 & 2047;
        if (t == 2) {
          bf16x4 v4 = { (__bf16)acc[r][c][0], (__bf16)acc[r][c][1],
                        (__bf16)acc[r][c][2], (__bf16)acc[r][c][3] };
          *reinterpret_cast<uintx2*>(&vtb[(((size_t)(h * 4 + b)) * 128 + d) * 2048 + s0]) =
              __builtin_bit_cast(uintx2, v4);
        } else {
          unsigned short* base = t ? kb : qb;
          #pragma unroll
          for (int j = 0; j < 4; ++j)
            base[(((size_t)(h * 4 + b)) * 2048 + s0 + j) * 128 + d] = f2bf(acc[r][c][j]);
        }
      }
    }
  }
}

// ---------------------------------------------------------------------------
// Causal flash attention. q,k: [hb][s][128] bf16 (roped); vt: [hb][d][s] bf16.
// Output a: [b*2048+s][h*128+d] bf16. QBLK=64 (16 rows/wave), KBLK=64.
// T14 async reg-staged prefetch of next K/V tile; T5 setprio; T13 defer-max.
__global__ __launch_bounds__(256)
void attn_kernel(const unsigned short* __restrict__ q,
                 const unsigned short* __restrict__ k,
                 const unsigned short* __restrict__ vt,
                 unsigned short* __restrict__ a) {
  const int hb = blockIdx.x;            // h*4 + b
  const int h = hb >> 2, b = hb & 3;
  const int qb = 31 - blockIdx.y;       // heavy blocks first
  const int q0 = qb * 64;
  const int tid = threadIdx.x, w = tid >> 6, lane = tid & 63;
  const int l15 = lane & 15, l4 = lane >> 4;

  __shared__ unsigned short Klds[64 * 128];   // XOR-swizzled rows
  __shared__ unsigned short Vlds[128 * 64];   // vt tile, XOR-swizzled rows
  __shared__ unsigned short Plds[4][16 * 64]; // per-wave P, swizzled

  const size_t qkbase = (size_t)hb * 2048 * 128;
  const size_t vtbase = (size_t)hb * 128 * 2048;
  const int qw_min = q0 + w * 16;
  const float scale = 0.08838834764831845f;   // 1/sqrt(128)
  const int nt = qb + 1;

  bf16x8 qf[4];
  #pragma unroll
  for (int ks = 0; ks < 4; ++ks)
    qf[ks] = ld_frag(&q[qkbase + (size_t)(qw_min + l15) * 128 + ks * 32 + l4 * 8]);

  uintx4 kreg[4], vreg[4];
  auto issue = [&](int kt) {
    #pragma unroll
    for (int i = 0; i < 4; ++i) {
      const int slot = tid + i * 256;
      kreg[i] = *reinterpret_cast<const uintx4*>(
          &k[qkbase + (size_t)(kt + (slot >> 4)) * 128 + (slot & 15) * 8]);
      vreg[i] = *reinterpret_cast<const uintx4*>(
          &vt[vtbase + (size_t)(slot >> 3) * 2048 + kt + (slot & 7) * 8]);
    }
  };
  auto commit = [&]() {
    #pragma unroll
    for (int i = 0; i < 4; ++i) {
      const int slot = tid + i * 256;
      const int kr = slot >> 4, kc = (slot & 15) * 8;
      *reinterpret_cast<uintx4*>(&Klds[kr * 128 + (kc ^ ((kr & 7) << 3))]) = kreg[i];
      const int vr = slot >> 3, vc = (slot & 7) * 8;
      *reinterpret_cast<uintx4*>(&Vlds[vr * 64 + (vc ^ ((vr & 7) << 3))]) = vreg[i];
    }
  };

  float m[4], lsum[4];
  f32x4 acco[8];
  const f32x4 z = {0.f, 0.f, 0.f, 0.f};
  #pragma unroll
  for (int j = 0; j < 4; ++j) { m[j] = -1e30f; lsum[j] = 0.f; }
  #pragma unroll
  for (int d2 = 0; d2 < 8; ++d2) acco[d2] = z;

  issue(0);
  commit();
  __syncthreads();

  for (int t = 0; t < nt; ++t) {
    const int kt = t * 64;
    if (t + 1 < nt) issue(kt + 64);     // prefetch next tile under compute

    // S = Q @ K^T  (per wave: 16q x 64kv)
    f32x4 sc[4];
    #pragma unroll
    for (int c = 0; c < 4; ++c) sc[c] = z;
    __builtin_amdgcn_s_setprio(1);
    #pragma unroll
    for (int c = 0; c < 4; ++c) {
      const int kr = c * 16 + l15;
      #pragma unroll
      for (int ks = 0; ks < 4; ++ks) {
        bf16x8 kf = ld_frag(&Klds[kr * 128 + ((l4 * 8 + ks * 32) ^ ((kr & 7) << 3))]);
        sc[c] = __builtin_amdgcn_mfma_f32_16x16x32_bf16(qf[ks], kf, sc[c], 0, 0, 0);
      }
    }
    __builtin_amdgcn_s_setprio(0);

    // scale + causal mask
    #pragma unroll
    for (int c = 0; c < 4; ++c) {
      const int kvg = kt + c * 16 + l15;
      #pragma unroll
      for (int j = 0; j < 4; ++j) {
        const int qg = qw_min + l4 * 4 + j;
        float s = sc[c][j] * scale;
        sc[c][j] = (kvg > qg) ? -1e30f : s;
      }
    }
    // online softmax, defer-max (THR=8)
    float mx[4];
    #pragma unroll
    for (int j = 0; j < 4; ++j)
      mx[j] = fmaxf(fmaxf(sc[0][j], sc[1][j]), fmaxf(sc[2][j], sc[3][j]));
    #pragma unroll
    for (int off = 1; off < 16; off <<= 1)
      #pragma unroll
      for (int j = 0; j < 4; ++j) mx[j] = fmaxf(mx[j], __shfl_xor(mx[j], off));
    bool need = false;
    #pragma unroll
    for (int j = 0; j < 4; ++j) need |= (mx[j] > m[j] + 8.0f);
    if (__any(need)) {
      #pragma unroll
      for (int j = 0; j < 4; ++j) {
        float nm = fmaxf(m[j], mx[j]);
        float al = __expf(m[j] - nm);
        m[j] = nm;
        lsum[j] *= al;
        #pragma unroll
        for (int d2 = 0; d2 < 8; ++d2) acco[d2][j] *= al;
      }
    }
    float rs[4] = {0.f, 0.f, 0.f, 0.f};
    #pragma unroll
    for (int c = 0; c < 4; ++c)
      #pragma unroll
      for (int j = 0; j < 4; ++j) {
        float p = __expf(sc[c][j] - m[j]);
        sc[c][j] = p;
        rs[j] += p;
      }
    #pragma unroll
    for (int off = 1; off < 16; off <<= 1)
      #pragma unroll
      for (int j = 0; j < 4; ++j) rs[j] += __shfl_xor(rs[j], off);
    #pragma unroll
    for (int j = 0; j < 4; ++j) lsum[j] += rs[j];

    // P -> LDS (bf16, swizzled; per-wave private, no barrier needed)
    #pragma unroll
    for (int c = 0; c < 4; ++c)
      #pragma unroll
      for (int j = 0; j < 4; ++j) {
        const int qr = l4 * 4 + j;
        const int kv = c * 16 + l15;
        Plds[w][qr * 64 + (kv ^ ((qr & 7) << 3))] = f2bf(sc[c][j]);
      }
    // O += P @ V
    __builtin_amdgcn_s_setprio(1);
    #pragma unroll
    for (int g = 0; g < 2; ++g) {
      bf16x8 pf = ld_frag(&Plds[w][l15 * 64 + ((g * 32 + l4 * 8) ^ ((l15 & 7) << 3))]);
      #pragma unroll
      for (int d2 = 0; d2 < 8; ++d2) {
        const int dr = d2 * 16 + l15;
        bf16x8 vf = ld_frag(&Vlds[dr * 64 + ((g * 32 + l4 * 8) ^ ((dr & 7) << 3))]);
        acco[d2] = __builtin_amdgcn_mfma_f32_16x16x32_bf16(pf, vf, acco[d2], 0, 0, 0);
      }
    }
    __builtin_amdgcn_s_setprio(0);

    __syncthreads();                    // all waves done with K/V LDS
    if (t + 1 < nt) {
      commit();                         // waits vmcnt, writes next tile
      __syncthreads();
    }
  }

  // normalize + write a[b*2048+s][h*128+d] bf16
  #pragma unroll
  for (int j = 0; j < 4; ++j) {
    const float inv = 1.0f / lsum[j];
    const int sr = qw_min + l4 * 4 + j;
    const size_t abase = ((size_t)(b * 2048 + sr)) * 2048 + h * 128;
    #pragma unroll
    for (int d2 = 0; d2 < 8; ++d2)
      a[abase + d2 * 16 + l15] = f2bf(acco[d2][j] * inv);
  }
}

// ---------------------------------------------------------------------------
extern "C" void kernel_launch(void* const* d_in, const int* in_sizes, int n_in,
                              void* d_out, int out_size, void* d_ws, size_t ws_size,
                              hipStream_t stream) {
  const float* x = (const float*)d_in[0];
  const float* wqkv = (const float*)d_in[1];
  const float* wout = (const float*)d_in[2];
  float* out = (float*)d_out;
  char* ws = (char*)d_ws;
  char* ob = (char*)d_out;

  // ws (128 MiB): q, k, vt, a  (w_out bf16 reuses dead q region at the end)
  unsigned short* qbuf = (unsigned short*)(ws + 0);
  unsigned short* kbuf = (unsigned short*)(ws + 33554432);
  unsigned short* vtb  = (unsigned short*)(ws + 67108864);
  unsigned short* abuf = (unsigned short*)(ws + 100663296);
  unsigned short* woutb = qbuf;  // converted AFTER attn (q dead by then)
  // d_out (64 MB) as scratch until the final GEMM overwrites it:
  unsigned short* xb    = (unsigned short*)(ob + 0);          // 33.5 MB
  unsigned short* wqkvb = (unsigned short*)(ob + 33554432);   // 25.2 MB
  float2*         tab   = (float2*)(ob + 58720256);           // 1 MB

  hipLaunchKernelGGL(cvt_bf16, dim3(8192), dim3(256), 0, stream, x, xb, 2097152);
  hipLaunchKernelGGL(cvt_bf16, dim3(6144), dim3(256), 0, stream, wqkv, wqkvb, 1572864);
  hipLaunchKernelGGL(rope_table, dim3(512), dim3(256), 0, stream, tab);
  // QKV projection: q,k -> [hb][s][d]; V scattered transposed -> vt [hb][d][s]
  hipLaunchKernelGGL((gemm_bf16<1>), dim3(3072), dim3(256), 0, stream,
                     xb, wqkvb, nullptr, qbuf, kbuf, vtb, 8192, 6144, 2048, 48);
  hipLaunchKernelGGL(rope_kernel, dim3(16384), dim3(256), 0, stream,
                     qbuf, kbuf, (const float2*)tab);
  hipLaunchKernelGGL(attn_kernel, dim3(64, 32), dim3(256), 0, stream,
                     qbuf, kbuf, vtb, abuf);
  hipLaunchKernelGGL(cvt_bf16, dim3(2048), dim3(256), 0, stream, wout, woutb, 524288);
  hipLaunchKernelGGL((gemm_bf16<0>), dim3(1024), dim3(256), 0, stream,
                     abuf, woutb, out, nullptr, nullptr, nullptr, 8192, 2048, 2048, 16);
}

// Round 4
// 571.926 us; speedup vs baseline: 1.4942x; 1.0156x over previous
//
#include <hip/hip_runtime.h>
#include <hip/hip_bf16.h>

typedef __attribute__((ext_vector_type(8))) __bf16 bf16x8;
typedef __attribute__((ext_vector_type(4))) __bf16 bf16x4;
typedef __attribute__((ext_vector_type(4))) float f32x4;
typedef __attribute__((ext_vector_type(4))) unsigned int uintx4;
typedef __attribute__((ext_vector_type(2))) unsigned int uintx2;

__device__ __forceinline__ unsigned short f2bf(float f) {
  __bf16 h = (__bf16)f;
  return __builtin_bit_cast(unsigned short, h);
}
__device__ __forceinline__ float bf2f(unsigned short u) {
  unsigned int x = ((unsigned int)u) << 16;
  return __builtin_bit_cast(float, x);
}
__device__ __forceinline__ bf16x8 ld_frag(const unsigned short* p) {
  return __builtin_bit_cast(bf16x8, *reinterpret_cast<const uintx4*>(p));
}
__device__ __forceinline__ uintx2 cvt4(float4 v) {
  bf16x4 h = { (__bf16)v.x, (__bf16)v.y, (__bf16)v.z, (__bf16)v.w };
  return __builtin_bit_cast(uintx2, h);
}
// async global->LDS, 16B per lane; lds dest must be wave-uniform base
__device__ __forceinline__ void gload16(const unsigned short* g, unsigned short* l) {
  __builtin_amdgcn_global_load_lds(
      (const __attribute__((address_space(1))) void*)g,
      (__attribute__((address_space(3))) void*)l, 16, 0, 0);
}

// ---------------------------------------------------------------------------
// fp32 -> bf16 bulk convert, 8 elems/thread
__global__ __launch_bounds__(256)
void cvt_bf16(const float* __restrict__ in, unsigned short* __restrict__ out, int n8) {
  int gid = blockIdx.x * 256 + threadIdx.x;
  if (gid >= n8) return;
  const float4* p = reinterpret_cast<const float4*>(in) + (size_t)gid * 2;
  float4 a = p[0], b = p[1];
  uintx2 lo = cvt4(a), hi = cvt4(b);
  uintx4 o = { lo[0], lo[1], hi[0], hi[1] };
  *(reinterpret_cast<uintx4*>(out) + gid) = o;
}

// ---------------------------------------------------------------------------
// RoPE cos/sin table: [s][i] for s in [0,2048), i in [0,64)
__global__ __launch_bounds__(256)
void rope_table(float2* __restrict__ tab) {
  int gid = blockIdx.x * 256 + threadIdx.x;   // 131072 total
  int i = gid & 63, s = gid >> 6;
  double inv = pow(10000.0, -(double)i / 64.0);
  double ang = (double)s * inv;
  tab[gid] = make_float2((float)cos(ang), (float)sin(ang));
}

// ---------------------------------------------------------------------------
// In-place RoPE on q and k buffers, layout [hb][s][128] bf16, 8 elems/thread
__global__ __launch_bounds__(256)
void rope_kernel(unsigned short* __restrict__ qb, unsigned short* __restrict__ kb,
                 const float2* __restrict__ tab) {
  int gid = blockIdx.x * 256 + threadIdx.x;   // 4,194,304 total
  int g = gid & 15;
  int s = (gid >> 4) & 2047;
  int hb = (gid >> 15) & 63;
  unsigned short* base = (gid >> 21) ? kb : qb;
  size_t off = (((size_t)hb * 2048 + s) * 128) + g * 8;
  union { uintx4 u; unsigned short sh[8]; } v;
  v.u = *reinterpret_cast<const uintx4*>(base + off);
  #pragma unroll
  for (int p = 0; p < 4; ++p) {
    float2 cs = tab[s * 64 + g * 4 + p];
    float x1 = bf2f(v.sh[2 * p]), x2 = bf2f(v.sh[2 * p + 1]);
    float r1 = x1 * cs.x - x2 * cs.y;
    float r2 = x1 * cs.y + x2 * cs.x;
    v.sh[2 * p] = f2bf(r1);
    v.sh[2 * p + 1] = f2bf(r2);
  }
  *reinterpret_cast<uintx4*>(base + off) = v.u;
}

// ---------------------------------------------------------------------------
// Pipelined GEMM C[M][N] = A[M][K] @ B[N][K]^T, bf16 in.
// BM=256 BN=128 BK=64, 512 thr (8 waves 2Mx4N), 3 LDS buffers, 2-tile-deep
// prefetch, counted vmcnt(6) (T4 - never drains), setprio around MFMA (T5),
// global_load_lds w16 with pre-swizzled source + XOR-swizzled ds_read.
// EPI=0: fp32 C.  EPI=1: scatter bf16 q/k [hb][s][128] + V transposed [hb][d][s].
template<int EPI>
__global__ __launch_bounds__(512, 2)
void gemm_pipe(const unsigned short* __restrict__ A, const unsigned short* __restrict__ B,
               float* __restrict__ C,
               unsigned short* __restrict__ qb, unsigned short* __restrict__ kb,
               unsigned short* __restrict__ vtb, int M, int N, int K, int nbx) {
  __shared__ unsigned short Alds[3][256 * 64];   // 96 KiB
  __shared__ unsigned short Blds[3][128 * 64];   // 48 KiB
  const int nwg = gridDim.x;
  const int bid = blockIdx.x;
  const int swz = (bid & 7) * (nwg >> 3) + (bid >> 3);
  const int n0 = (swz % nbx) * 128, m0 = (swz / nbx) * 256;
  const int tid = threadIdx.x, lane = tid & 63, w = tid >> 6;
  const int wr = w >> 2, wc = w & 3, l15 = lane & 15, l4 = lane >> 4;

  auto stage = [&](int kt, int buf) {
    #pragma unroll
    for (int i = 0; i < 4; ++i) {               // A: 256x64 = 2048 chunks
      const int q = i * 512 + tid;
      const int row = q >> 3, slot = q & 7;
      gload16(&A[(size_t)(m0 + row) * K + kt + ((slot ^ (row & 7)) << 3)],
              &Alds[buf][(i * 512 + w * 64) * 8]);
    }
    #pragma unroll
    for (int i = 0; i < 2; ++i) {               // B: 128x64 = 1024 chunks
      const int q = i * 512 + tid;
      const int row = q >> 3, slot = q & 7;
      gload16(&B[(size_t)(n0 + row) * K + kt + ((slot ^ (row & 7)) << 3)],
              &Blds[buf][(i * 512 + w * 64) * 8]);
    }
  };

  const f32x4 z = {0.f, 0.f, 0.f, 0.f};
  f32x4 acc[8][2];
  #pragma unroll
  for (int mi = 0; mi < 8; ++mi)
    #pragma unroll
    for (int ni = 0; ni < 2; ++ni) acc[mi][ni] = z;

  const int NT = K >> 6;
  stage(0, 0);
  stage(64, 1);

  int bc = 0;                                    // buffer of current tile
  for (int t = 0; t < NT; ++t) {
    // tile t's 6 loads landed; tile t+1's 6 may stay in flight (never drain)
    asm volatile("s_waitcnt vmcnt(6)" ::: "memory");
    __builtin_amdgcn_s_barrier();
    asm volatile("" ::: "memory");
    if (t + 2 < NT) {
      int bs = bc + 2; if (bs >= 3) bs -= 3;
      stage((t + 2) * 64, bs);
    }
    const unsigned short* Ab = &Alds[bc][0];
    const unsigned short* Bb = &Blds[bc][0];
    bf16x8 bfr[2][2];
    #pragma unroll
    for (int ni = 0; ni < 2; ++ni) {
      const int Rb = wc * 32 + ni * 16 + l15;
      #pragma unroll
      for (int kk = 0; kk < 2; ++kk)
        bfr[kk][ni] = ld_frag(&Bb[Rb * 64 + ((kk * 32 + l4 * 8) ^ ((Rb & 7) << 3))]);
    }
    __builtin_amdgcn_s_setprio(1);
    #pragma unroll
    for (int mi = 0; mi < 8; ++mi) {
      const int Ra = wr * 128 + mi * 16 + l15;
      bf16x8 a0 = ld_frag(&Ab[Ra * 64 + ((l4 * 8) ^ ((Ra & 7) << 3))]);
      bf16x8 a1 = ld_frag(&Ab[Ra * 64 + ((32 + l4 * 8) ^ ((Ra & 7) << 3))]);
      #pragma unroll
      for (int ni = 0; ni < 2; ++ni) {
        acc[mi][ni] = __builtin_amdgcn_mfma_f32_16x16x32_bf16(a0, bfr[0][ni], acc[mi][ni], 0, 0, 0);
        acc[mi][ni] = __builtin_amdgcn_mfma_f32_16x16x32_bf16(a1, bfr[1][ni], acc[mi][ni], 0, 0, 0);
      }
    }
    __builtin_amdgcn_s_setprio(0);
    bc = (bc + 1 == 3) ? 0 : bc + 1;
  }

  if constexpr (EPI == 0) {
    #pragma unroll
    for (int mi = 0; mi < 8; ++mi)
      #pragma unroll
      for (int ni = 0; ni < 2; ++ni) {
        const int col = n0 + wc * 32 + ni * 16 + l15;
        #pragma unroll
        for (int j = 0; j < 4; ++j) {
          const int row = m0 + wr * 128 + mi * 16 + l4 * 4 + j;
          C[(size_t)row * N + col] = acc[mi][ni][j];
        }
      }
  } else {
    #pragma unroll
    for (int ni = 0; ni < 2; ++ni) {
      const int col = n0 + wc * 32 + ni * 16 + l15;
      const int t = col >> 11, h = (col >> 7) & 15, d = col & 127;
      #pragma unroll
      for (int mi = 0; mi < 8; ++mi) {
        const int row0 = m0 + wr * 128 + mi * 16 + l4 * 4;
        const int b = row0 >> 11, s0 = row0 & 2047;
        if (t == 2) {
          bf16x4 v4 = { (__bf16)acc[mi][ni][0], (__bf16)acc[mi][ni][1],
                        (__bf16)acc[mi][ni][2], (__bf16)acc[mi][ni][3] };
          *reinterpret_cast<uintx2*>(&vtb[(((size_t)(h * 4 + b)) * 128 + d) * 2048 + s0]) =
              __builtin_bit_cast(uintx2, v4);
        } else {
          unsigned short* base = t ? kb : qb;
          #pragma unroll
          for (int j = 0; j < 4; ++j)
            base[(((size_t)(h * 4 + b)) * 2048 + s0 + j) * 128 + d] = f2bf(acc[mi][ni][j]);
        }
      }
    }
  }
}

// ---------------------------------------------------------------------------
// Causal flash attention. q,k: [hb][s][128] bf16 (roped); vt: [hb][d][s] bf16.
// Output a: [b*2048+s][h*128+d] bf16. QBLK=64 (16 rows/wave), KBLK=64.
// T14 async reg-staged prefetch of next K/V tile; T5 setprio; T13 defer-max.
__global__ __launch_bounds__(256)
void attn_kernel(const unsigned short* __restrict__ q,
                 const unsigned short* __restrict__ k,
                 const unsigned short* __restrict__ vt,
                 unsigned short* __restrict__ a) {
  const int hb = blockIdx.x;            // h*4 + b
  const int h = hb >> 2, b = hb & 3;
  const int qb = 31 - blockIdx.y;       // heavy blocks first
  const int q0 = qb * 64;
  const int tid = threadIdx.x, w = tid >> 6, lane = tid & 63;
  const int l15 = lane & 15, l4 = lane >> 4;

  __shared__ unsigned short Klds[64 * 128];   // XOR-swizzled rows
  __shared__ unsigned short Vlds[128 * 64];   // vt tile, XOR-swizzled rows
  __shared__ unsigned short Plds[4][16 * 64]; // per-wave P, swizzled

  const size_t qkbase = (size_t)hb * 2048 * 128;
  const size_t vtbase = (size_t)hb * 128 * 2048;
  const int qw_min = q0 + w * 16;
  const float scale = 0.08838834764831845f;   // 1/sqrt(128)
  const int nt = qb + 1;

  bf16x8 qf[4];
  #pragma unroll
  for (int ks = 0; ks < 4; ++ks)
    qf[ks] = ld_frag(&q[qkbase + (size_t)(qw_min + l15) * 128 + ks * 32 + l4 * 8]);

  uintx4 kreg[4], vreg[4];
  auto issue = [&](int kt) {
    #pragma unroll
    for (int i = 0; i < 4; ++i) {
      const int slot = tid + i * 256;
      kreg[i] = *reinterpret_cast<const uintx4*>(
          &k[qkbase + (size_t)(kt + (slot >> 4)) * 128 + (slot & 15) * 8]);
      vreg[i] = *reinterpret_cast<const uintx4*>(
          &vt[vtbase + (size_t)(slot >> 3) * 2048 + kt + (slot & 7) * 8]);
    }
  };
  auto commit = [&]() {
    #pragma unroll
    for (int i = 0; i < 4; ++i) {
      const int slot = tid + i * 256;
      const int kr = slot >> 4, kc = (slot & 15) * 8;
      *reinterpret_cast<uintx4*>(&Klds[kr * 128 + (kc ^ ((kr & 7) << 3))]) = kreg[i];
      const int vr = slot >> 3, vc = (slot & 7) * 8;
      *reinterpret_cast<uintx4*>(&Vlds[vr * 64 + (vc ^ ((vr & 7) << 3))]) = vreg[i];
    }
  };

  float m[4], lsum[4];
  f32x4 acco[8];
  const f32x4 z = {0.f, 0.f, 0.f, 0.f};
  #pragma unroll
  for (int j = 0; j < 4; ++j) { m[j] = -1e30f; lsum[j] = 0.f; }
  #pragma unroll
  for (int d2 = 0; d2 < 8; ++d2) acco[d2] = z;

  issue(0);
  commit();
  __syncthreads();

  for (int t = 0; t < nt; ++t) {
    const int kt = t * 64;
    if (t + 1 < nt) issue(kt + 64);     // prefetch next tile under compute

    // S = Q @ K^T  (per wave: 16q x 64kv)
    f32x4 sc[4];
    #pragma unroll
    for (int c = 0; c < 4; ++c) sc[c] = z;
    __builtin_amdgcn_s_setprio(1);
    #pragma unroll
    for (int c = 0; c < 4; ++c) {
      const int kr = c * 16 + l15;
      #pragma unroll
      for (int ks = 0; ks < 4; ++ks) {
        bf16x8 kf = ld_frag(&Klds[kr * 128 + ((l4 * 8 + ks * 32) ^ ((kr & 7) << 3))]);
        sc[c] = __builtin_amdgcn_mfma_f32_16x16x32_bf16(qf[ks], kf, sc[c], 0, 0, 0);
      }
    }
    __builtin_amdgcn_s_setprio(0);

    // scale + causal mask
    #pragma unroll
    for (int c = 0; c < 4; ++c) {
      const int kvg = kt + c * 16 + l15;
      #pragma unroll
      for (int j = 0; j < 4; ++j) {
        const int qg = qw_min + l4 * 4 + j;
        float s = sc[c][j] * scale;
        sc[c][j] = (kvg > qg) ? -1e30f : s;
      }
    }
    // online softmax, defer-max (THR=8)
    float mx[4];
    #pragma unroll
    for (int j = 0; j < 4; ++j)
      mx[j] = fmaxf(fmaxf(sc[0][j], sc[1][j]), fmaxf(sc[2][j], sc[3][j]));
    #pragma unroll
    for (int off = 1; off < 16; off <<= 1)
      #pragma unroll
      for (int j = 0; j < 4; ++j) mx[j] = fmaxf(mx[j], __shfl_xor(mx[j], off));
    bool need = false;
    #pragma unroll
    for (int j = 0; j < 4; ++j) need |= (mx[j] > m[j] + 8.0f);
    if (__any(need)) {
      #pragma unroll
      for (int j = 0; j < 4; ++j) {
        float nm = fmaxf(m[j], mx[j]);
        float al = __expf(m[j] - nm);
        m[j] = nm;
        lsum[j] *= al;
        #pragma unroll
        for (int d2 = 0; d2 < 8; ++d2) acco[d2][j] *= al;
      }
    }
    float rs[4] = {0.f, 0.f, 0.f, 0.f};
    #pragma unroll
    for (int c = 0; c < 4; ++c)
      #pragma unroll
      for (int j = 0; j < 4; ++j) {
        float p = __expf(sc[c][j] - m[j]);
        sc[c][j] = p;
        rs[j] += p;
      }
    #pragma unroll
    for (int off = 1; off < 16; off <<= 1)
      #pragma unroll
      for (int j = 0; j < 4; ++j) rs[j] += __shfl_xor(rs[j], off);
    #pragma unroll
    for (int j = 0; j < 4; ++j) lsum[j] += rs[j];

    // P -> LDS (bf16, swizzled; per-wave private, no barrier needed)
    #pragma unroll
    for (int c = 0; c < 4; ++c)
      #pragma unroll
      for (int j = 0; j < 4; ++j) {
        const int qr = l4 * 4 + j;
        const int kv = c * 16 + l15;
        Plds[w][qr * 64 + (kv ^ ((qr & 7) << 3))] = f2bf(sc[c][j]);
      }
    // O += P @ V
    __builtin_amdgcn_s_setprio(1);
    #pragma unroll
    for (int g = 0; g < 2; ++g) {
      bf16x8 pf = ld_frag(&Plds[w][l15 * 64 + ((g * 32 + l4 * 8) ^ ((l15 & 7) << 3))]);
      #pragma unroll
      for (int d2 = 0; d2 < 8; ++d2) {
        const int dr = d2 * 16 + l15;
        bf16x8 vf = ld_frag(&Vlds[dr * 64 + ((g * 32 + l4 * 8) ^ ((dr & 7) << 3))]);
        acco[d2] = __builtin_amdgcn_mfma_f32_16x16x32_bf16(pf, vf, acco[d2], 0, 0, 0);
      }
    }
    __builtin_amdgcn_s_setprio(0);

    __syncthreads();                    // all waves done with K/V LDS
    if (t + 1 < nt) {
      commit();                         // waits vmcnt, writes next tile
      __syncthreads();
    }
  }

  // normalize + write a[b*2048+s][h*128+d] bf16
  #pragma unroll
  for (int j = 0; j < 4; ++j) {
    const float inv = 1.0f / lsum[j];
    const int sr = qw_min + l4 * 4 + j;
    const size_t abase = ((size_t)(b * 2048 + sr)) * 2048 + h * 128;
    #pragma unroll
    for (int d2 = 0; d2 < 8; ++d2)
      a[abase + d2 * 16 + l15] = f2bf(acco[d2][j] * inv);
  }
}

// ---------------------------------------------------------------------------
extern "C" void kernel_launch(void* const* d_in, const int* in_sizes, int n_in,
                              void* d_out, int out_size, void* d_ws, size_t ws_size,
                              hipStream_t stream) {
  const float* x = (const float*)d_in[0];
  const float* wqkv = (const float*)d_in[1];
  const float* wout = (const float*)d_in[2];
  float* out = (float*)d_out;
  char* ws = (char*)d_ws;
  char* ob = (char*)d_out;

  // ws (128 MiB): q, k, vt, a  (w_out bf16 reuses dead q region at the end)
  unsigned short* qbuf = (unsigned short*)(ws + 0);
  unsigned short* kbuf = (unsigned short*)(ws + 33554432);
  unsigned short* vtb  = (unsigned short*)(ws + 67108864);
  unsigned short* abuf = (unsigned short*)(ws + 100663296);
  unsigned short* woutb = qbuf;  // converted AFTER attn (q dead by then)
  // d_out (64 MB) as scratch until the final GEMM overwrites it:
  unsigned short* xb    = (unsigned short*)(ob + 0);          // 33.5 MB
  unsigned short* wqkvb = (unsigned short*)(ob + 33554432);   // 25.2 MB
  float2*         tab   = (float2*)(ob + 58720256);           // 1 MB

  hipLaunchKernelGGL(cvt_bf16, dim3(8192), dim3(256), 0, stream, x, xb, 2097152);
  hipLaunchKernelGGL(cvt_bf16, dim3(6144), dim3(256), 0, stream, wqkv, wqkvb, 1572864);
  hipLaunchKernelGGL(rope_table, dim3(512), dim3(256), 0, stream, tab);
  // QKV projection: q,k -> [hb][s][d]; V scattered transposed -> vt [hb][d][s]
  hipLaunchKernelGGL((gemm_pipe<1>), dim3(1536), dim3(512), 0, stream,
                     xb, wqkvb, nullptr, qbuf, kbuf, vtb, 8192, 6144, 2048, 48);
  hipLaunchKernelGGL(rope_kernel, dim3(16384), dim3(256), 0, stream,
                     qbuf, kbuf, (const float2*)tab);
  hipLaunchKernelGGL(attn_kernel, dim3(64, 32), dim3(256), 0, stream,
                     qbuf, kbuf, vtb, abuf);
  hipLaunchKernelGGL(cvt_bf16, dim3(2048), dim3(256), 0, stream, wout, woutb, 524288);
  hipLaunchKernelGGL((gemm_pipe<0>), dim3(512), dim3(512), 0, stream,
                     abuf, woutb, out, nullptr, nullptr, nullptr, 8192, 2048, 2048, 16);
}

// Round 5
// 502.891 us; speedup vs baseline: 1.6994x; 1.1373x over previous
//
#include <hip/hip_runtime.h>
#include <hip/hip_bf16.h>

typedef __attribute__((ext_vector_type(8))) __bf16 bf16x8;
typedef __attribute__((ext_vector_type(4))) __bf16 bf16x4;
typedef __attribute__((ext_vector_type(4))) float f32x4;
typedef __attribute__((ext_vector_type(4))) unsigned int uintx4;
typedef __attribute__((ext_vector_type(2))) unsigned int uintx2;

__device__ __forceinline__ unsigned short f2bf(float f) {
  __bf16 h = (__bf16)f;
  return __builtin_bit_cast(unsigned short, h);
}
__device__ __forceinline__ float bf2f(unsigned short u) {
  unsigned int x = ((unsigned int)u) << 16;
  return __builtin_bit_cast(float, x);
}
__device__ __forceinline__ bf16x8 ld_frag(const unsigned short* p) {
  return __builtin_bit_cast(bf16x8, *reinterpret_cast<const uintx4*>(p));
}
__device__ __forceinline__ uintx2 cvt4(float4 v) {
  bf16x4 h = { (__bf16)v.x, (__bf16)v.y, (__bf16)v.z, (__bf16)v.w };
  return __builtin_bit_cast(uintx2, h);
}
// async global->LDS, 16B per lane; lds dest must be wave-uniform base
__device__ __forceinline__ void gload16(const unsigned short* g, unsigned short* l) {
  __builtin_amdgcn_global_load_lds(
      (const __attribute__((address_space(1))) void*)g,
      (__attribute__((address_space(3))) void*)l, 16, 0, 0);
}

// ---------------------------------------------------------------------------
// fp32 -> bf16 bulk convert, 8 elems/thread
__global__ __launch_bounds__(256)
void cvt_bf16(const float* __restrict__ in, unsigned short* __restrict__ out, int n8) {
  int gid = blockIdx.x * 256 + threadIdx.x;
  if (gid >= n8) return;
  const float4* p = reinterpret_cast<const float4*>(in) + (size_t)gid * 2;
  float4 a = p[0], b = p[1];
  uintx2 lo = cvt4(a), hi = cvt4(b);
  uintx4 o = { lo[0], lo[1], hi[0], hi[1] };
  *(reinterpret_cast<uintx4*>(out) + gid) = o;
}

// ---------------------------------------------------------------------------
// RoPE cos/sin table: [s][i] for s in [0,2048), i in [0,64)
__global__ __launch_bounds__(256)
void rope_table(float2* __restrict__ tab) {
  int gid = blockIdx.x * 256 + threadIdx.x;   // 131072 total
  int i = gid & 63, s = gid >> 6;
  double inv = pow(10000.0, -(double)i / 64.0);
  double ang = (double)s * inv;
  tab[gid] = make_float2((float)cos(ang), (float)sin(ang));
}

// ---------------------------------------------------------------------------
// In-place RoPE on q and k buffers, layout [hb][s][128] bf16, 8 elems/thread
__global__ __launch_bounds__(256)
void rope_kernel(unsigned short* __restrict__ qb, unsigned short* __restrict__ kb,
                 const float2* __restrict__ tab) {
  int gid = blockIdx.x * 256 + threadIdx.x;   // 4,194,304 total
  int g = gid & 15;
  int s = (gid >> 4) & 2047;
  int hb = (gid >> 15) & 63;
  unsigned short* base = (gid >> 21) ? kb : qb;
  size_t off = (((size_t)hb * 2048 + s) * 128) + g * 8;
  union { uintx4 u; unsigned short sh[8]; } v;
  v.u = *reinterpret_cast<const uintx4*>(base + off);
  #pragma unroll
  for (int p = 0; p < 4; ++p) {
    float2 cs = tab[s * 64 + g * 4 + p];
    float x1 = bf2f(v.sh[2 * p]), x2 = bf2f(v.sh[2 * p + 1]);
    float r1 = x1 * cs.x - x2 * cs.y;
    float r2 = x1 * cs.y + x2 * cs.x;
    v.sh[2 * p] = f2bf(r1);
    v.sh[2 * p + 1] = f2bf(r2);
  }
  *reinterpret_cast<uintx4*>(base + off) = v.u;
}

// ---------------------------------------------------------------------------
// 8-phase GEMM C[M][N] = A[M][K] @ B[N][K]^T, bf16 in (m201-style).
// BM=BN=256, BK=64, 512 thr (8 waves 2Mx4N), per-wave 128x64 out.
// 2 LDS buffers; per K-tile 4 quadrant-phases, each {ds_read frags | stage
// half-pair -> barrier -> lgkmcnt(0) -> setprio 16xMFMA -> barrier};
// vmcnt(4) once per tile before barrier (counted, never drains to 0).
// Stage windows: {Am0,Bn0}(J) at q3 of J-2; {Bn1,Am1}(J) at q0 of J-1.
// EPI=0: fp32 C.  EPI=1: scatter bf16 q/k [hb][s][128] + V transposed [hb][d][s].
template<int EPI>
__global__ __launch_bounds__(512, 1)
void gemm8(const unsigned short* __restrict__ A, const unsigned short* __restrict__ B,
           float* __restrict__ C, unsigned short* __restrict__ qb,
           unsigned short* __restrict__ kb, unsigned short* __restrict__ vtb,
           int M, int N, int K, int nbx) {
  __shared__ unsigned short Al[2][256 * 64];   // 64 KiB
  __shared__ unsigned short Bl[2][256 * 64];   // 64 KiB
  const int nwg = gridDim.x, bid = blockIdx.x;
  const int swz = (bid & 7) * (nwg >> 3) + (bid >> 3);
  const int n0 = (swz % nbx) * 256, m0 = (swz / nbx) * 256;
  const int tid = threadIdx.x, lane = tid & 63, w = tid >> 6;
  const int wr = w >> 2, wc = w & 3, l15 = lane & 15, l4 = lane >> 4;
  const int NT = K >> 6;

  // stage one 128x64-short half: global rows [gr0, gr0+128), dest LDS base
  auto stage_half = [&](const unsigned short* src, int gr0, unsigned short* ldsb, int kt) {
    #pragma unroll
    for (int i = 0; i < 2; ++i) {
      const int rb = (w * 2 + i) * 8;                 // wave-uniform row base
      const int R = rb + (lane >> 3);
      const int cs = ((lane & 7) * 8) ^ ((R & 7) << 3);  // pre-swizzled src col
      gload16(&src[(size_t)(gr0 + R) * K + kt + cs], &ldsb[rb * 64]);
    }
  };
  auto sp_a0b0 = [&](int J) {   // halves {Am0, Bn0} of tile J
    const int buf = J & 1, kt = J * 64;
    stage_half(A, m0, &Al[buf][0], kt);
    stage_half(B, n0, &Bl[buf][0], kt);
  };
  auto sp_b1a1 = [&](int J) {   // halves {Bn1, Am1} of tile J
    const int buf = J & 1, kt = J * 64;
    stage_half(B, n0 + 128, &Bl[buf][128 * 64], kt);
    stage_half(A, m0 + 128, &Al[buf][128 * 64], kt);
  };

  f32x4 acc[8][4];
  const f32x4 z = {0.f, 0.f, 0.f, 0.f};
  #pragma unroll
  for (int mi = 0; mi < 8; ++mi)
    #pragma unroll
    for (int ni = 0; ni < 4; ++ni) acc[mi][ni] = z;

  bf16x8 aF[4][2], bF[4][2];
  auto ldA = [&](int buf, int mh) {
    #pragma unroll
    for (int i = 0; i < 4; ++i) {
      const int R = wr * 128 + (mh * 4 + i) * 16 + l15;
      #pragma unroll
      for (int kk = 0; kk < 2; ++kk)
        aF[i][kk] = ld_frag(&Al[buf][R * 64 + ((kk * 32 + l4 * 8) ^ ((R & 7) << 3))]);
    }
  };
  auto ldB = [&](int buf, int nh) {
    #pragma unroll
    for (int i = 0; i < 2; ++i) {
      const int R = wc * 64 + (nh * 2 + i) * 16 + l15;
      #pragma unroll
      for (int kk = 0; kk < 2; ++kk)
        bF[nh * 2 + i][kk] = ld_frag(&Bl[buf][R * 64 + ((kk * 32 + l4 * 8) ^ ((R & 7) << 3))]);
    }
  };
  auto mm = [&](int mh, int nh) {
    __builtin_amdgcn_s_setprio(1);
    #pragma unroll
    for (int i = 0; i < 4; ++i)
      #pragma unroll
      for (int ii = 0; ii < 2; ++ii)
        #pragma unroll
        for (int kk = 0; kk < 2; ++kk)
          acc[mh * 4 + i][nh * 2 + ii] = __builtin_amdgcn_mfma_f32_16x16x32_bf16(
              aF[i][kk], bF[nh * 2 + ii][kk], acc[mh * 4 + i][nh * 2 + ii], 0, 0, 0);
    __builtin_amdgcn_s_setprio(0);
  };

  // prologue: tile0 fully + tile1's first half-pair; wait tile0 landed
  sp_a0b0(0); sp_b1a1(0); sp_a0b0(1);
  asm volatile("s_waitcnt vmcnt(4)" ::: "memory");
  __builtin_amdgcn_s_barrier();

  for (int J = 0; J < NT; ++J) {
    const int buf = J & 1;
    // ---- q0: quadrant (m-half0, n-half0); stage {Bn1,Am1} of J+1
    ldA(buf, 0);
    ldB(buf, 0);
    if (J + 1 < NT) sp_b1a1(J + 1);
    __builtin_amdgcn_s_barrier();
    asm volatile("s_waitcnt lgkmcnt(0)" ::: "memory");
    mm(0, 0);
    __builtin_amdgcn_s_barrier();
    // ---- q1: quadrant (m0, n-half1)
    ldB(buf, 1);
    __builtin_amdgcn_s_barrier();
    asm volatile("s_waitcnt lgkmcnt(0)" ::: "memory");
    mm(0, 1);
    __builtin_amdgcn_s_barrier();
    // ---- q2: quadrant (m-half1, n0)
    ldA(buf, 1);
    __builtin_amdgcn_s_barrier();
    asm volatile("s_waitcnt lgkmcnt(0)" ::: "memory");
    mm(1, 0);
    __builtin_amdgcn_s_barrier();
    // ---- q3: quadrant (m1, n1); stage {Am0,Bn0} of J+2; counted vmcnt
    if (J + 2 < NT) sp_a0b0(J + 2);
    asm volatile("s_waitcnt vmcnt(4)" ::: "memory");
    __builtin_amdgcn_s_barrier();
    mm(1, 1);
    __builtin_amdgcn_s_barrier();
  }

  if constexpr (EPI == 0) {
    #pragma unroll
    for (int mi = 0; mi < 8; ++mi)
      #pragma unroll
      for (int ni = 0; ni < 4; ++ni) {
        const int col = n0 + wc * 64 + ni * 16 + l15;
        #pragma unroll
        for (int j = 0; j < 4; ++j) {
          const int row = m0 + wr * 128 + mi * 16 + l4 * 4 + j;
          C[(size_t)row * N + col] = acc[mi][ni][j];
        }
      }
  } else {
    #pragma unroll
    for (int ni = 0; ni < 4; ++ni) {
      const int col = n0 + wc * 64 + ni * 16 + l15;
      const int t = col >> 11, h = (col >> 7) & 15, d = col & 127;
      #pragma unroll
      for (int mi = 0; mi < 8; ++mi) {
        const int row0 = m0 + wr * 128 + mi * 16 + l4 * 4;
        const int b = row0 >> 11, s0 = row0 & 2047;
        if (t == 2) {
          bf16x4 v4 = { (__bf16)acc[mi][ni][0], (__bf16)acc[mi][ni][1],
                        (__bf16)acc[mi][ni][2], (__bf16)acc[mi][ni][3] };
          *reinterpret_cast<uintx2*>(&vtb[(((size_t)(h * 4 + b)) * 128 + d) * 2048 + s0]) =
              __builtin_bit_cast(uintx2, v4);
        } else {
          unsigned short* base = t ? kb : qb;
          #pragma unroll
          for (int j = 0; j < 4; ++j)
            base[(((size_t)(h * 4 + b)) * 2048 + s0 + j) * 128 + d] = f2bf(acc[mi][ni][j]);
        }
      }
    }
  }
}

// ---------------------------------------------------------------------------
// Causal flash attention. q,k: [hb][s][128] bf16 (roped); vt: [hb][d][s] bf16.
// Output a: [b*2048+s][h*128+d] bf16. QBLK=64 (16 rows/wave), KBLK=64.
// T14 async reg-staged prefetch of next K/V tile; T5 setprio; T13 defer-max.
__global__ __launch_bounds__(256)
void attn_kernel(const unsigned short* __restrict__ q,
                 const unsigned short* __restrict__ k,
                 const unsigned short* __restrict__ vt,
                 unsigned short* __restrict__ a) {
  const int hb = blockIdx.x;            // h*4 + b
  const int h = hb >> 2, b = hb & 3;
  const int qb = 31 - blockIdx.y;       // heavy blocks first
  const int q0 = qb * 64;
  const int tid = threadIdx.x, w = tid >> 6, lane = tid & 63;
  const int l15 = lane & 15, l4 = lane >> 4;

  __shared__ unsigned short Klds[64 * 128];   // XOR-swizzled rows
  __shared__ unsigned short Vlds[128 * 64];   // vt tile, XOR-swizzled rows
  __shared__ unsigned short Plds[4][16 * 64]; // per-wave P, swizzled

  const size_t qkbase = (size_t)hb * 2048 * 128;
  const size_t vtbase = (size_t)hb * 128 * 2048;
  const int qw_min = q0 + w * 16;
  const float scale = 0.08838834764831845f;   // 1/sqrt(128)
  const int nt = qb + 1;

  bf16x8 qf[4];
  #pragma unroll
  for (int ks = 0; ks < 4; ++ks)
    qf[ks] = ld_frag(&q[qkbase + (size_t)(qw_min + l15) * 128 + ks * 32 + l4 * 8]);

  uintx4 kreg[4], vreg[4];
  auto issue = [&](int kt) {
    #pragma unroll
    for (int i = 0; i < 4; ++i) {
      const int slot = tid + i * 256;
      kreg[i] = *reinterpret_cast<const uintx4*>(
          &k[qkbase + (size_t)(kt + (slot >> 4)) * 128 + (slot & 15) * 8]);
      vreg[i] = *reinterpret_cast<const uintx4*>(
          &vt[vtbase + (size_t)(slot >> 3) * 2048 + kt + (slot & 7) * 8]);
    }
  };
  auto commit = [&]() {
    #pragma unroll
    for (int i = 0; i < 4; ++i) {
      const int slot = tid + i * 256;
      const int kr = slot >> 4, kc = (slot & 15) * 8;
      *reinterpret_cast<uintx4*>(&Klds[kr * 128 + (kc ^ ((kr & 7) << 3))]) = kreg[i];
      const int vr = slot >> 3, vc = (slot & 7) * 8;
      *reinterpret_cast<uintx4*>(&Vlds[vr * 64 + (vc ^ ((vr & 7) << 3))]) = vreg[i];
    }
  };

  float m[4], lsum[4];
  f32x4 acco[8];
  const f32x4 z = {0.f, 0.f, 0.f, 0.f};
  #pragma unroll
  for (int j = 0; j < 4; ++j) { m[j] = -1e30f; lsum[j] = 0.f; }
  #pragma unroll
  for (int d2 = 0; d2 < 8; ++d2) acco[d2] = z;

  issue(0);
  commit();
  __syncthreads();

  for (int t = 0; t < nt; ++t) {
    const int kt = t * 64;
    if (t + 1 < nt) issue(kt + 64);     // prefetch next tile under compute

    // S = Q @ K^T  (per wave: 16q x 64kv)
    f32x4 sc[4];
    #pragma unroll
    for (int c = 0; c < 4; ++c) sc[c] = z;
    __builtin_amdgcn_s_setprio(1);
    #pragma unroll
    for (int c = 0; c < 4; ++c) {
      const int kr = c * 16 + l15;
      #pragma unroll
      for (int ks = 0; ks < 4; ++ks) {
        bf16x8 kf = ld_frag(&Klds[kr * 128 + ((l4 * 8 + ks * 32) ^ ((kr & 7) << 3))]);
        sc[c] = __builtin_amdgcn_mfma_f32_16x16x32_bf16(qf[ks], kf, sc[c], 0, 0, 0);
      }
    }
    __builtin_amdgcn_s_setprio(0);

    // scale + causal mask
    #pragma unroll
    for (int c = 0; c < 4; ++c) {
      const int kvg = kt + c * 16 + l15;
      #pragma unroll
      for (int j = 0; j < 4; ++j) {
        const int qg = qw_min + l4 * 4 + j;
        float s = sc[c][j] * scale;
        sc[c][j] = (kvg > qg) ? -1e30f : s;
      }
    }
    // online softmax, defer-max (THR=8)
    float mx[4];
    #pragma unroll
    for (int j = 0; j < 4; ++j)
      mx[j] = fmaxf(fmaxf(sc[0][j], sc[1][j]), fmaxf(sc[2][j], sc[3][j]));
    #pragma unroll
    for (int off = 1; off < 16; off <<= 1)
      #pragma unroll
      for (int j = 0; j < 4; ++j) mx[j] = fmaxf(mx[j], __shfl_xor(mx[j], off));
    bool need = false;
    #pragma unroll
    for (int j = 0; j < 4; ++j) need |= (mx[j] > m[j] + 8.0f);
    if (__any(need)) {
      #pragma unroll
      for (int j = 0; j < 4; ++j) {
        float nm = fmaxf(m[j], mx[j]);
        float al = __expf(m[j] - nm);
        m[j] = nm;
        lsum[j] *= al;
        #pragma unroll
        for (int d2 = 0; d2 < 8; ++d2) acco[d2][j] *= al;
      }
    }
    float rs[4] = {0.f, 0.f, 0.f, 0.f};
    #pragma unroll
    for (int c = 0; c < 4; ++c)
      #pragma unroll
      for (int j = 0; j < 4; ++j) {
        float p = __expf(sc[c][j] - m[j]);
        sc[c][j] = p;
        rs[j] += p;
      }
    #pragma unroll
    for (int off = 1; off < 16; off <<= 1)
      #pragma unroll
      for (int j = 0; j < 4; ++j) rs[j] += __shfl_xor(rs[j], off);
    #pragma unroll
    for (int j = 0; j < 4; ++j) lsum[j] += rs[j];

    // P -> LDS (bf16, swizzled; per-wave private, no barrier needed)
    #pragma unroll
    for (int c = 0; c < 4; ++c)
      #pragma unroll
      for (int j = 0; j < 4; ++j) {
        const int qr = l4 * 4 + j;
        const int kv = c * 16 + l15;
        Plds[w][qr * 64 + (kv ^ ((qr & 7) << 3))] = f2bf(sc[c][j]);
      }
    // O += P @ V
    __builtin_amdgcn_s_setprio(1);
    #pragma unroll
    for (int g = 0; g < 2; ++g) {
      bf16x8 pf = ld_frag(&Plds[w][l15 * 64 + ((g * 32 + l4 * 8) ^ ((l15 & 7) << 3))]);
      #pragma unroll
      for (int d2 = 0; d2 < 8; ++d2) {
        const int dr = d2 * 16 + l15;
        bf16x8 vf = ld_frag(&Vlds[dr * 64 + ((g * 32 + l4 * 8) ^ ((dr & 7) << 3))]);
        acco[d2] = __builtin_amdgcn_mfma_f32_16x16x32_bf16(pf, vf, acco[d2], 0, 0, 0);
      }
    }
    __builtin_amdgcn_s_setprio(0);

    __syncthreads();                    // all waves done with K/V LDS
    if (t + 1 < nt) {
      commit();                         // waits vmcnt, writes next tile
      __syncthreads();
    }
  }

  // normalize + write a[b*2048+s][h*128+d] bf16
  #pragma unroll
  for (int j = 0; j < 4; ++j) {
    const float inv = 1.0f / lsum[j];
    const int sr = qw_min + l4 * 4 + j;
    const size_t abase = ((size_t)(b * 2048 + sr)) * 2048 + h * 128;
    #pragma unroll
    for (int d2 = 0; d2 < 8; ++d2)
      a[abase + d2 * 16 + l15] = f2bf(acco[d2][j] * inv);
  }
}

// ---------------------------------------------------------------------------
extern "C" void kernel_launch(void* const* d_in, const int* in_sizes, int n_in,
                              void* d_out, int out_size, void* d_ws, size_t ws_size,
                              hipStream_t stream) {
  const float* x = (const float*)d_in[0];
  const float* wqkv = (const float*)d_in[1];
  const float* wout = (const float*)d_in[2];
  float* out = (float*)d_out;
  char* ws = (char*)d_ws;
  char* ob = (char*)d_out;

  // ws (128 MiB): q, k, vt, a  (w_out bf16 reuses dead q region at the end)
  unsigned short* qbuf = (unsigned short*)(ws + 0);
  unsigned short* kbuf = (unsigned short*)(ws + 33554432);
  unsigned short* vtb  = (unsigned short*)(ws + 67108864);
  unsigned short* abuf = (unsigned short*)(ws + 100663296);
  unsigned short* woutb = qbuf;  // converted AFTER attn (q dead by then)
  // d_out (64 MB) as scratch until the final GEMM overwrites it:
  unsigned short* xb    = (unsigned short*)(ob + 0);          // 33.5 MB
  unsigned short* wqkvb = (unsigned short*)(ob + 33554432);   // 25.2 MB
  float2*         tab   = (float2*)(ob + 58720256);           // 1 MB

  hipLaunchKernelGGL(cvt_bf16, dim3(8192), dim3(256), 0, stream, x, xb, 2097152);
  hipLaunchKernelGGL(cvt_bf16, dim3(6144), dim3(256), 0, stream, wqkv, wqkvb, 1572864);
  hipLaunchKernelGGL(rope_table, dim3(512), dim3(256), 0, stream, tab);
  // QKV projection: q,k -> [hb][s][d]; V scattered transposed -> vt [hb][d][s]
  hipLaunchKernelGGL((gemm8<1>), dim3(768), dim3(512), 0, stream,
                     xb, wqkvb, nullptr, qbuf, kbuf, vtb, 8192, 6144, 2048, 24);
  hipLaunchKernelGGL(rope_kernel, dim3(16384), dim3(256), 0, stream,
                     qbuf, kbuf, (const float2*)tab);
  hipLaunchKernelGGL(attn_kernel, dim3(64, 32), dim3(256), 0, stream,
                     qbuf, kbuf, vtb, abuf);
  hipLaunchKernelGGL(cvt_bf16, dim3(2048), dim3(256), 0, stream, wout, woutb, 524288);
  hipLaunchKernelGGL((gemm8<0>), dim3(256), dim3(512), 0, stream,
                     abuf, woutb, out, nullptr, nullptr, nullptr, 8192, 2048, 2048, 8);
}

// Round 6
// 497.373 us; speedup vs baseline: 1.7182x; 1.0111x over previous
//
#include <hip/hip_runtime.h>
#include <hip/hip_bf16.h>

typedef __attribute__((ext_vector_type(8))) __bf16 bf16x8;
typedef __attribute__((ext_vector_type(4))) __bf16 bf16x4;
typedef __attribute__((ext_vector_type(4))) float f32x4;
typedef __attribute__((ext_vector_type(4))) unsigned int uintx4;
typedef __attribute__((ext_vector_type(2))) unsigned int uintx2;

__device__ __forceinline__ unsigned short f2bf(float f) {
  __bf16 h = (__bf16)f;
  return __builtin_bit_cast(unsigned short, h);
}
__device__ __forceinline__ float bf2f(unsigned short u) {
  unsigned int x = ((unsigned int)u) << 16;
  return __builtin_bit_cast(float, x);
}
__device__ __forceinline__ bf16x8 ld_frag(const unsigned short* p) {
  return __builtin_bit_cast(bf16x8, *reinterpret_cast<const uintx4*>(p));
}
__device__ __forceinline__ uintx2 cvt4(float4 v) {
  bf16x4 h = { (__bf16)v.x, (__bf16)v.y, (__bf16)v.z, (__bf16)v.w };
  return __builtin_bit_cast(uintx2, h);
}
// async global->LDS, 16B per lane; lds dest must be wave-uniform base
__device__ __forceinline__ void gload16(const unsigned short* g, unsigned short* l) {
  __builtin_amdgcn_global_load_lds(
      (const __attribute__((address_space(1))) void*)g,
      (__attribute__((address_space(3))) void*)l, 16, 0, 0);
}

__device__ __forceinline__ void cvt8(const float* in, unsigned short* out, int gid) {
  const float4* p = reinterpret_cast<const float4*>(in) + (size_t)gid * 2;
  float4 a = p[0], b = p[1];
  uintx2 lo = cvt4(a), hi = cvt4(b);
  uintx4 o = { lo[0], lo[1], hi[0], hi[1] };
  *(reinterpret_cast<uintx4*>(out) + gid) = o;
}

// ---------------------------------------------------------------------------
// Fused prep: cvt x (8192 blocks) + cvt w_qkv (6144 blocks) + rope table (512)
__global__ __launch_bounds__(256)
void prep(const float* __restrict__ x, unsigned short* __restrict__ xb,
          const float* __restrict__ wqkv, unsigned short* __restrict__ wqkvb,
          float2* __restrict__ tab) {
  const int bid = blockIdx.x, tid = threadIdx.x;
  if (bid < 8192) {
    cvt8(x, xb, bid * 256 + tid);
  } else if (bid < 14336) {
    cvt8(wqkv, wqkvb, (bid - 8192) * 256 + tid);
  } else {
    int gid = (bid - 14336) * 256 + tid;   // 131072 total
    int i = gid & 63, s = gid >> 6;
    double inv = pow(10000.0, -(double)i / 64.0);
    double ang = (double)s * inv;
    tab[gid] = make_float2((float)cos(ang), (float)sin(ang));
  }
}

// fp32 -> bf16 bulk convert, 8 elems/thread
__global__ __launch_bounds__(256)
void cvt_bf16(const float* __restrict__ in, unsigned short* __restrict__ out, int n8) {
  int gid = blockIdx.x * 256 + threadIdx.x;
  if (gid >= n8) return;
  cvt8(in, out, gid);
}

// ---------------------------------------------------------------------------
// In-place RoPE on q and k buffers, layout [hb][s][128] bf16, 8 elems/thread
__global__ __launch_bounds__(256)
void rope_kernel(unsigned short* __restrict__ qb, unsigned short* __restrict__ kb,
                 const float2* __restrict__ tab) {
  int gid = blockIdx.x * 256 + threadIdx.x;   // 4,194,304 total
  int g = gid & 15;
  int s = (gid >> 4) & 2047;
  int hb = (gid >> 15) & 63;
  unsigned short* base = (gid >> 21) ? kb : qb;
  size_t off = (((size_t)hb * 2048 + s) * 128) + g * 8;
  union { uintx4 u; unsigned short sh[8]; } v;
  v.u = *reinterpret_cast<const uintx4*>(base + off);
  #pragma unroll
  for (int p = 0; p < 4; ++p) {
    float2 cs = tab[s * 64 + g * 4 + p];
    float x1 = bf2f(v.sh[2 * p]), x2 = bf2f(v.sh[2 * p + 1]);
    float r1 = x1 * cs.x - x2 * cs.y;
    float r2 = x1 * cs.y + x2 * cs.x;
    v.sh[2 * p] = f2bf(r1);
    v.sh[2 * p + 1] = f2bf(r2);
  }
  *reinterpret_cast<uintx4*>(base + off) = v.u;
}

// ---------------------------------------------------------------------------
// 8-phase GEMM C[M][N] = A[M][K] @ B[N][K]^T, bf16 in (m201-style).
// BM=BN=256, BK=64, 512 thr (8 waves 2Mx4N), per-wave 128x64 out.
// (unchanged from round 5 — current local best, 888 TF)
template<int EPI>
__global__ __launch_bounds__(512, 1)
void gemm8(const unsigned short* __restrict__ A, const unsigned short* __restrict__ B,
           float* __restrict__ C, unsigned short* __restrict__ qb,
           unsigned short* __restrict__ kb, unsigned short* __restrict__ vtb,
           int M, int N, int K, int nbx) {
  __shared__ unsigned short Al[2][256 * 64];   // 64 KiB
  __shared__ unsigned short Bl[2][256 * 64];   // 64 KiB
  const int nwg = gridDim.x, bid = blockIdx.x;
  const int swz = (bid & 7) * (nwg >> 3) + (bid >> 3);
  const int n0 = (swz % nbx) * 256, m0 = (swz / nbx) * 256;
  const int tid = threadIdx.x, lane = tid & 63, w = tid >> 6;
  const int wr = w >> 2, wc = w & 3, l15 = lane & 15, l4 = lane >> 4;
  const int NT = K >> 6;

  auto stage_half = [&](const unsigned short* src, int gr0, unsigned short* ldsb, int kt) {
    #pragma unroll
    for (int i = 0; i < 2; ++i) {
      const int rb = (w * 2 + i) * 8;                 // wave-uniform row base
      const int R = rb + (lane >> 3);
      const int cs = ((lane & 7) * 8) ^ ((R & 7) << 3);  // pre-swizzled src col
      gload16(&src[(size_t)(gr0 + R) * K + kt + cs], &ldsb[rb * 64]);
    }
  };
  auto sp_a0b0 = [&](int J) {   // halves {Am0, Bn0} of tile J
    const int buf = J & 1, kt = J * 64;
    stage_half(A, m0, &Al[buf][0], kt);
    stage_half(B, n0, &Bl[buf][0], kt);
  };
  auto sp_b1a1 = [&](int J) {   // halves {Bn1, Am1} of tile J
    const int buf = J & 1, kt = J * 64;
    stage_half(B, n0 + 128, &Bl[buf][128 * 64], kt);
    stage_half(A, m0 + 128, &Al[buf][128 * 64], kt);
  };

  f32x4 acc[8][4];
  const f32x4 z = {0.f, 0.f, 0.f, 0.f};
  #pragma unroll
  for (int mi = 0; mi < 8; ++mi)
    #pragma unroll
    for (int ni = 0; ni < 4; ++ni) acc[mi][ni] = z;

  bf16x8 aF[4][2], bF[4][2];
  auto ldA = [&](int buf, int mh) {
    #pragma unroll
    for (int i = 0; i < 4; ++i) {
      const int R = wr * 128 + (mh * 4 + i) * 16 + l15;
      #pragma unroll
      for (int kk = 0; kk < 2; ++kk)
        aF[i][kk] = ld_frag(&Al[buf][R * 64 + ((kk * 32 + l4 * 8) ^ ((R & 7) << 3))]);
    }
  };
  auto ldB = [&](int buf, int nh) {
    #pragma unroll
    for (int i = 0; i < 2; ++i) {
      const int R = wc * 64 + (nh * 2 + i) * 16 + l15;
      #pragma unroll
      for (int kk = 0; kk < 2; ++kk)
        bF[nh * 2 + i][kk] = ld_frag(&Bl[buf][R * 64 + ((kk * 32 + l4 * 8) ^ ((R & 7) << 3))]);
    }
  };
  auto mm = [&](int mh, int nh) {
    __builtin_amdgcn_s_setprio(1);
    #pragma unroll
    for (int i = 0; i < 4; ++i)
      #pragma unroll
      for (int ii = 0; ii < 2; ++ii)
        #pragma unroll
        for (int kk = 0; kk < 2; ++kk)
          acc[mh * 4 + i][nh * 2 + ii] = __builtin_amdgcn_mfma_f32_16x16x32_bf16(
              aF[i][kk], bF[nh * 2 + ii][kk], acc[mh * 4 + i][nh * 2 + ii], 0, 0, 0);
    __builtin_amdgcn_s_setprio(0);
  };

  sp_a0b0(0); sp_b1a1(0); sp_a0b0(1);
  asm volatile("s_waitcnt vmcnt(4)" ::: "memory");
  __builtin_amdgcn_s_barrier();

  for (int J = 0; J < NT; ++J) {
    const int buf = J & 1;
    ldA(buf, 0);
    ldB(buf, 0);
    if (J + 1 < NT) sp_b1a1(J + 1);
    __builtin_amdgcn_s_barrier();
    asm volatile("s_waitcnt lgkmcnt(0)" ::: "memory");
    mm(0, 0);
    __builtin_amdgcn_s_barrier();
    ldB(buf, 1);
    __builtin_amdgcn_s_barrier();
    asm volatile("s_waitcnt lgkmcnt(0)" ::: "memory");
    mm(0, 1);
    __builtin_amdgcn_s_barrier();
    ldA(buf, 1);
    __builtin_amdgcn_s_barrier();
    asm volatile("s_waitcnt lgkmcnt(0)" ::: "memory");
    mm(1, 0);
    __builtin_amdgcn_s_barrier();
    if (J + 2 < NT) sp_a0b0(J + 2);
    asm volatile("s_waitcnt vmcnt(4)" ::: "memory");
    __builtin_amdgcn_s_barrier();
    mm(1, 1);
    __builtin_amdgcn_s_barrier();
  }

  if constexpr (EPI == 0) {
    #pragma unroll
    for (int mi = 0; mi < 8; ++mi)
      #pragma unroll
      for (int ni = 0; ni < 4; ++ni) {
        const int col = n0 + wc * 64 + ni * 16 + l15;
        #pragma unroll
        for (int j = 0; j < 4; ++j) {
          const int row = m0 + wr * 128 + mi * 16 + l4 * 4 + j;
          C[(size_t)row * N + col] = acc[mi][ni][j];
        }
      }
  } else {
    #pragma unroll
    for (int ni = 0; ni < 4; ++ni) {
      const int col = n0 + wc * 64 + ni * 16 + l15;
      const int t = col >> 11, h = (col >> 7) & 15, d = col & 127;
      #pragma unroll
      for (int mi = 0; mi < 8; ++mi) {
        const int row0 = m0 + wr * 128 + mi * 16 + l4 * 4;
        const int b = row0 >> 11, s0 = row0 & 2047;
        if (t == 2) {
          bf16x4 v4 = { (__bf16)acc[mi][ni][0], (__bf16)acc[mi][ni][1],
                        (__bf16)acc[mi][ni][2], (__bf16)acc[mi][ni][3] };
          *reinterpret_cast<uintx2*>(&vtb[(((size_t)(h * 4 + b)) * 128 + d) * 2048 + s0]) =
              __builtin_bit_cast(uintx2, v4);
        } else {
          unsigned short* base = t ? kb : qb;
          #pragma unroll
          for (int j = 0; j < 4; ++j)
            base[(((size_t)(h * 4 + b)) * 2048 + s0 + j) * 128 + d] = f2bf(acc[mi][ni][j]);
        }
      }
    }
  }
}

// ---------------------------------------------------------------------------
// Causal flash attention. q,k: [hb][s][128] bf16 (roped); vt: [hb][d][s] bf16.
// Output a: [b*2048+s][h*128+d] bf16. QBLK=128 (8 waves x 16 rows), KBLK=64.
// Each staged K/V tile serves 128 q-rows (2x round-5) -> staging/barriers per
// unit work halved. T14 async reg prefetch; T5 setprio; T13 defer-max.
__global__ __launch_bounds__(512)
void attn_kernel(const unsigned short* __restrict__ q,
                 const unsigned short* __restrict__ k,
                 const unsigned short* __restrict__ vt,
                 unsigned short* __restrict__ a) {
  const int hb = blockIdx.x;            // h*4 + b
  const int h = hb >> 2, b = hb & 3;
  const int Q = 15 - blockIdx.y;        // heavy blocks first
  const int q0 = Q * 128;
  const int tid = threadIdx.x, w = tid >> 6, lane = tid & 63;
  const int l15 = lane & 15, l4 = lane >> 4;

  __shared__ unsigned short Klds[64 * 128];   // XOR-swizzled rows, 16 KB
  __shared__ unsigned short Vlds[128 * 64];   // vt tile, swizzled, 16 KB
  __shared__ unsigned short Plds[8][16 * 64]; // per-wave P, swizzled, 16 KB

  const size_t qkbase = (size_t)hb * 2048 * 128;
  const size_t vtbase = (size_t)hb * 128 * 2048;
  const int qw_min = q0 + w * 16;
  const float scale = 0.08838834764831845f;   // 1/sqrt(128)
  const int nt = 2 * Q + 2;

  bf16x8 qf[4];
  #pragma unroll
  for (int ks = 0; ks < 4; ++ks)
    qf[ks] = ld_frag(&q[qkbase + (size_t)(qw_min + l15) * 128 + ks * 32 + l4 * 8]);

  uintx4 kreg[2], vreg[2];
  auto issue = [&](int kt) {
    #pragma unroll
    for (int i = 0; i < 2; ++i) {
      const int slot = tid + i * 512;
      kreg[i] = *reinterpret_cast<const uintx4*>(
          &k[qkbase + (size_t)(kt + (slot >> 4)) * 128 + (slot & 15) * 8]);
      vreg[i] = *reinterpret_cast<const uintx4*>(
          &vt[vtbase + (size_t)(slot >> 3) * 2048 + kt + (slot & 7) * 8]);
    }
  };
  auto commit = [&]() {
    #pragma unroll
    for (int i = 0; i < 2; ++i) {
      const int slot = tid + i * 512;
      const int kr = slot >> 4, kc = (slot & 15) * 8;
      *reinterpret_cast<uintx4*>(&Klds[kr * 128 + (kc ^ ((kr & 7) << 3))]) = kreg[i];
      const int vr = slot >> 3, vc = (slot & 7) * 8;
      *reinterpret_cast<uintx4*>(&Vlds[vr * 64 + (vc ^ ((vr & 7) << 3))]) = vreg[i];
    }
  };

  float m[4], lsum[4];
  f32x4 acco[8];
  const f32x4 z = {0.f, 0.f, 0.f, 0.f};
  #pragma unroll
  for (int j = 0; j < 4; ++j) { m[j] = -1e30f; lsum[j] = 0.f; }
  #pragma unroll
  for (int d2 = 0; d2 < 8; ++d2) acco[d2] = z;

  issue(0);
  commit();
  __syncthreads();

  for (int t = 0; t < nt; ++t) {
    const int kt = t * 64;
    if (t + 1 < nt) issue(kt + 64);     // prefetch next tile under compute

    // S = Q @ K^T  (per wave: 16q x 64kv)
    f32x4 sc[4];
    #pragma unroll
    for (int c = 0; c < 4; ++c) sc[c] = z;
    __builtin_amdgcn_s_setprio(1);
    #pragma unroll
    for (int c = 0; c < 4; ++c) {
      const int kr = c * 16 + l15;
      #pragma unroll
      for (int ks = 0; ks < 4; ++ks) {
        bf16x8 kf = ld_frag(&Klds[kr * 128 + ((l4 * 8 + ks * 32) ^ ((kr & 7) << 3))]);
        sc[c] = __builtin_amdgcn_mfma_f32_16x16x32_bf16(qf[ks], kf, sc[c], 0, 0, 0);
      }
    }
    __builtin_amdgcn_s_setprio(0);

    // scale + causal mask
    #pragma unroll
    for (int c = 0; c < 4; ++c) {
      const int kvg = kt + c * 16 + l15;
      #pragma unroll
      for (int j = 0; j < 4; ++j) {
        const int qg = qw_min + l4 * 4 + j;
        float s = sc[c][j] * scale;
        sc[c][j] = (kvg > qg) ? -1e30f : s;
      }
    }
    // online softmax, defer-max (THR=8)
    float mx[4];
    #pragma unroll
    for (int j = 0; j < 4; ++j)
      mx[j] = fmaxf(fmaxf(sc[0][j], sc[1][j]), fmaxf(sc[2][j], sc[3][j]));
    #pragma unroll
    for (int off = 1; off < 16; off <<= 1)
      #pragma unroll
      for (int j = 0; j < 4; ++j) mx[j] = fmaxf(mx[j], __shfl_xor(mx[j], off));
    bool need = false;
    #pragma unroll
    for (int j = 0; j < 4; ++j) need |= (mx[j] > m[j] + 8.0f);
    if (__any(need)) {
      #pragma unroll
      for (int j = 0; j < 4; ++j) {
        float nm = fmaxf(m[j], mx[j]);
        float al = __expf(m[j] - nm);
        m[j] = nm;
        lsum[j] *= al;
        #pragma unroll
        for (int d2 = 0; d2 < 8; ++d2) acco[d2][j] *= al;
      }
    }
    float rs[4] = {0.f, 0.f, 0.f, 0.f};
    #pragma unroll
    for (int c = 0; c < 4; ++c)
      #pragma unroll
      for (int j = 0; j < 4; ++j) {
        float p = __expf(sc[c][j] - m[j]);
        sc[c][j] = p;
        rs[j] += p;
      }
    #pragma unroll
    for (int off = 1; off < 16; off <<= 1)
      #pragma unroll
      for (int j = 0; j < 4; ++j) rs[j] += __shfl_xor(rs[j], off);
    #pragma unroll
    for (int j = 0; j < 4; ++j) lsum[j] += rs[j];

    // P -> LDS (bf16, swizzled; per-wave private, no barrier needed)
    #pragma unroll
    for (int c = 0; c < 4; ++c)
      #pragma unroll
      for (int j = 0; j < 4; ++j) {
        const int qr = l4 * 4 + j;
        const int kv = c * 16 + l15;
        Plds[w][qr * 64 + (kv ^ ((qr & 7) << 3))] = f2bf(sc[c][j]);
      }
    // O += P @ V
    __builtin_amdgcn_s_setprio(1);
    #pragma unroll
    for (int g = 0; g < 2; ++g) {
      bf16x8 pf = ld_frag(&Plds[w][l15 * 64 + ((g * 32 + l4 * 8) ^ ((l15 & 7) << 3))]);
      #pragma unroll
      for (int d2 = 0; d2 < 8; ++d2) {
        const int dr = d2 * 16 + l15;
        bf16x8 vf = ld_frag(&Vlds[dr * 64 + ((g * 32 + l4 * 8) ^ ((dr & 7) << 3))]);
        acco[d2] = __builtin_amdgcn_mfma_f32_16x16x32_bf16(pf, vf, acco[d2], 0, 0, 0);
      }
    }
    __builtin_amdgcn_s_setprio(0);

    __syncthreads();                    // all waves done with K/V LDS
    if (t + 1 < nt) {
      commit();                         // waits vmcnt, writes next tile
      __syncthreads();
    }
  }

  // normalize + write a[b*2048+s][h*128+d] bf16
  #pragma unroll
  for (int j = 0; j < 4; ++j) {
    const float inv = 1.0f / lsum[j];
    const int sr = qw_min + l4 * 4 + j;
    const size_t abase = ((size_t)(b * 2048 + sr)) * 2048 + h * 128;
    #pragma unroll
    for (int d2 = 0; d2 < 8; ++d2)
      a[abase + d2 * 16 + l15] = f2bf(acco[d2][j] * inv);
  }
}

// ---------------------------------------------------------------------------
extern "C" void kernel_launch(void* const* d_in, const int* in_sizes, int n_in,
                              void* d_out, int out_size, void* d_ws, size_t ws_size,
                              hipStream_t stream) {
  const float* x = (const float*)d_in[0];
  const float* wqkv = (const float*)d_in[1];
  const float* wout = (const float*)d_in[2];
  float* out = (float*)d_out;
  char* ws = (char*)d_ws;
  char* ob = (char*)d_out;

  // ws (128 MiB): q, k, vt, a  (w_out bf16 reuses dead q region at the end)
  unsigned short* qbuf = (unsigned short*)(ws + 0);
  unsigned short* kbuf = (unsigned short*)(ws + 33554432);
  unsigned short* vtb  = (unsigned short*)(ws + 67108864);
  unsigned short* abuf = (unsigned short*)(ws + 100663296);
  unsigned short* woutb = qbuf;  // converted AFTER attn (q dead by then)
  // d_out (64 MB) as scratch until the final GEMM overwrites it:
  unsigned short* xb    = (unsigned short*)(ob + 0);          // 33.5 MB
  unsigned short* wqkvb = (unsigned short*)(ob + 33554432);   // 25.2 MB
  float2*         tab   = (float2*)(ob + 58720256);           // 1 MB

  hipLaunchKernelGGL(prep, dim3(14848), dim3(256), 0, stream,
                     x, xb, wqkv, wqkvb, tab);
  // QKV projection: q,k -> [hb][s][d]; V scattered transposed -> vt [hb][d][s]
  hipLaunchKernelGGL((gemm8<1>), dim3(768), dim3(512), 0, stream,
                     xb, wqkvb, nullptr, qbuf, kbuf, vtb, 8192, 6144, 2048, 24);
  hipLaunchKernelGGL(rope_kernel, dim3(16384), dim3(256), 0, stream,
                     qbuf, kbuf, (const float2*)tab);
  hipLaunchKernelGGL(attn_kernel, dim3(64, 16), dim3(512), 0, stream,
                     qbuf, kbuf, vtb, abuf);
  hipLaunchKernelGGL(cvt_bf16, dim3(2048), dim3(256), 0, stream, wout, woutb, 524288);
  hipLaunchKernelGGL((gemm8<0>), dim3(256), dim3(512), 0, stream,
                     abuf, woutb, out, nullptr, nullptr, nullptr, 8192, 2048, 2048, 8);
}